// Round 1
// baseline (378.763 us; speedup 1.0000x reference)
//
#include <hip/hip_runtime.h>
#include <hip/hip_bf16.h>
#include <cstdint>
#include <cstddef>

#define T_TOK 4096
#define DIM   1024
#define NE    8
#define DFF   2048
#define NSLOT 8192   // T_TOK * TOP_K

typedef __bf16 bf16x8 __attribute__((ext_vector_type(8)));
typedef float  f32x4  __attribute__((ext_vector_type(4)));
typedef unsigned short u16;
typedef unsigned short u16x8 __attribute__((ext_vector_type(8)));

__device__ __forceinline__ u16 f2bf(float f) {
  union { float f; uint32_t u; } v; v.f = f;
  uint32_t r = (v.u + 0x7FFFu + ((v.u >> 16) & 1u)) >> 16;
  return (u16)r;
}

typedef const __attribute__((address_space(1))) uint32_t* gas_ptr;
typedef __attribute__((address_space(3))) uint32_t* las_ptr;
__device__ __forceinline__ void gl_lds16(const void* g, void* l) {
  __builtin_amdgcn_global_load_lds((gas_ptr)g, (las_ptr)l, 16, 0, 0);
}

// ---------------- conversion fp32 -> bf16 ----------------
__global__ __launch_bounds__(256) void cvt_kernel(const float* __restrict__ src,
                                                  u16* __restrict__ dst, long n) {
  long stride = (long)gridDim.x * 256 * 8;
  for (long i = ((long)blockIdx.x * 256 + threadIdx.x) * 8; i < n; i += stride) {
    float4 a = *(const float4*)(src + i);
    float4 b = *(const float4*)(src + i + 4);
    u16x8 r;
    r[0] = f2bf(a.x); r[1] = f2bf(a.y); r[2] = f2bf(a.z); r[3] = f2bf(a.w);
    r[4] = f2bf(b.x); r[5] = f2bf(b.y); r[6] = f2bf(b.z); r[7] = f2bf(b.w);
    *(u16x8*)(dst + i) = r;
  }
}

// ---------------- init ----------------
__global__ void init_kernel(int* counts) {
  if (threadIdx.x < NE) counts[threadIdx.x] = 0;
}

// ---------------- gate: scores (fp32), softmax, top-2 ----------------
__global__ __launch_bounds__(256) void gate_kernel(const float* __restrict__ x,
                                                   const float* __restrict__ gw,
                                                   int* __restrict__ idx,
                                                   float* __restrict__ wts,
                                                   int* __restrict__ counts) {
  __shared__ float sgw[NE * DIM];
  int tid = threadIdx.x;
  for (int i = tid; i < NE * DIM; i += 256) sgw[i] = gw[i];
  __syncthreads();
  int wave = tid >> 6, lane = tid & 63;
  int t = blockIdx.x * 4 + wave;
  float xv[16];
#pragma unroll
  for (int j = 0; j < 16; ++j) xv[j] = x[(size_t)t * DIM + lane + j * 64];
  float s[NE];
#pragma unroll
  for (int e = 0; e < NE; ++e) {
    float a = 0.f;
#pragma unroll
    for (int j = 0; j < 16; ++j) a += xv[j] * sgw[e * DIM + lane + j * 64];
    s[e] = a;
  }
#pragma unroll
  for (int off = 32; off > 0; off >>= 1) {
#pragma unroll
    for (int e = 0; e < NE; ++e) s[e] += __shfl_xor(s[e], off, 64);
  }
  if (lane == 0) {
    float m = s[0];
#pragma unroll
    for (int e = 1; e < NE; ++e) m = fmaxf(m, s[e]);
    float p[NE]; float sum = 0.f;
#pragma unroll
    for (int e = 0; e < NE; ++e) { p[e] = __expf(s[e] - m); sum += p[e]; }
    (void)sum;
    int i0 = 0;
#pragma unroll
    for (int e = 1; e < NE; ++e) if (s[e] > s[i0]) i0 = e;
    int i1 = (i0 == 0) ? 1 : 0;
#pragma unroll
    for (int e = 0; e < NE; ++e) if (e != i1 && e != i0 && s[e] > s[i1]) i1 = e;
    float p0 = p[i0], p1 = p[i1], inv = 1.f / (p0 + p1);
    idx[2 * t] = i0; idx[2 * t + 1] = i1;
    wts[2 * t] = p0 * inv; wts[2 * t + 1] = p1 * inv;
    atomicAdd(&counts[i0], 1);
    atomicAdd(&counts[i1], 1);
  }
}

// ---------------- scan ----------------
__global__ void scan_kernel(const int* __restrict__ counts, int* __restrict__ offs,
                            int* __restrict__ cursors) {
  if (threadIdx.x == 0) {
    int a = 0;
    for (int e = 0; e < NE; ++e) { offs[e] = a; cursors[e] = a; a += counts[e]; }
    offs[NE] = a;
  }
}

// ---------------- scatter ----------------
__global__ void scatter_kernel(const int* __restrict__ idx, const float* __restrict__ wts,
                               int* __restrict__ cursors, int* __restrict__ perm,
                               float* __restrict__ wt_slot, int* __restrict__ slot_of) {
  int t = blockIdx.x * blockDim.x + threadIdx.x;
  if (t < T_TOK) {
    for (int k = 0; k < 2; ++k) {
      int e = idx[2 * t + k];
      int pos = atomicAdd(&cursors[e], 1);
      perm[pos] = t;
      wt_slot[pos] = wts[2 * t + k];
      slot_of[2 * t + k] = pos;
    }
  }
}

// ---------------- ffn1: h = silu(X*W1^T) .* (X*W3^T), grouped by expert ----------------
__global__ __launch_bounds__(256, 2) void ffn1_kernel(
    const u16* __restrict__ xb, const u16* __restrict__ w1b, const u16* __restrict__ w3b,
    const int* __restrict__ offs, const int* __restrict__ perm, u16* __restrict__ h) {
  __shared__ u16 lA[128 * 32];
  __shared__ u16 lB1[128 * 32];
  __shared__ u16 lB3[128 * 32];
  int tid = threadIdx.x, wave = tid >> 6, lane = tid & 63;
  // which expert segment / M-block is this?
  int e = -1, mblk = 0;
  {
    int acc = 0;
    for (int i = 0; i < NE; ++i) {
      int c = offs[i + 1] - offs[i];
      int nb = (c + 127) >> 7;
      if ((int)blockIdx.y < acc + nb) { e = i; mblk = (int)blockIdx.y - acc; break; }
      acc += nb;
    }
  }
  if (e < 0) return;
  int seg = offs[e], cnt = offs[e + 1] - seg;
  int fBase = blockIdx.x * 128;
  int wr = wave >> 1, wc = wave & 1;
  // staging assignment: chunks c0,c1 (16 rows x 32 cols = 1024B each)
  int c0 = 2 * wave, c1 = 2 * wave + 1;
  int rc = lane >> 2, kk = (lane & 3) * 8;
  int lr0 = mblk * 128 + c0 * 16 + rc;
  int lr1 = mblk * 128 + c1 * 16 + rc;
  int ra0 = perm[seg + min(lr0, cnt - 1)];
  int ra1 = perm[seg + min(lr1, cnt - 1)];
  const u16* gA0 = xb + (size_t)ra0 * DIM + kk;
  const u16* gA1 = xb + (size_t)ra1 * DIM + kk;
  size_t wbase = (size_t)e * DFF * DIM;
  int f0 = fBase + c0 * 16 + rc, f1 = fBase + c1 * 16 + rc;
  const u16* gB1a = w1b + wbase + (size_t)f0 * DIM + kk;
  const u16* gB1b = w1b + wbase + (size_t)f1 * DIM + kk;
  const u16* gB3a = w3b + wbase + (size_t)f0 * DIM + kk;
  const u16* gB3b = w3b + wbase + (size_t)f1 * DIM + kk;

  f32x4 acc1[4][4], acc3[4][4];
#pragma unroll
  for (int i = 0; i < 4; ++i)
#pragma unroll
    for (int j = 0; j < 4; ++j) {
      acc1[i][j] = (f32x4){0.f, 0.f, 0.f, 0.f};
      acc3[i][j] = (f32x4){0.f, 0.f, 0.f, 0.f};
    }

  int aBase = (wr * 64 + (lane & 15)) * 32 + (lane >> 4) * 8;
  int bBase = (wc * 64 + (lane & 15)) * 32 + (lane >> 4) * 8;

  for (int k0 = 0; k0 < DIM; k0 += 32) {
    gl_lds16(gA0 + k0, &lA[c0 * 512]);
    gl_lds16(gA1 + k0, &lA[c1 * 512]);
    gl_lds16(gB1a + k0, &lB1[c0 * 512]);
    gl_lds16(gB1b + k0, &lB1[c1 * 512]);
    gl_lds16(gB3a + k0, &lB3[c0 * 512]);
    gl_lds16(gB3b + k0, &lB3[c1 * 512]);
    __syncthreads();
    bf16x8 af[4], b1f[4], b3f[4];
#pragma unroll
    for (int i = 0; i < 4; ++i) {
      af[i]  = *(const bf16x8*)&lA[aBase + i * 512];
      b1f[i] = *(const bf16x8*)&lB1[bBase + i * 512];
      b3f[i] = *(const bf16x8*)&lB3[bBase + i * 512];
    }
#pragma unroll
    for (int mi = 0; mi < 4; ++mi)
#pragma unroll
      for (int ni = 0; ni < 4; ++ni) {
        acc1[mi][ni] = __builtin_amdgcn_mfma_f32_16x16x32_bf16(af[mi], b1f[ni], acc1[mi][ni], 0, 0, 0);
        acc3[mi][ni] = __builtin_amdgcn_mfma_f32_16x16x32_bf16(af[mi], b3f[ni], acc3[mi][ni], 0, 0, 0);
      }
    __syncthreads();
  }
  // epilogue: silu(c1)*c3 -> h  (C/D layout: col=lane&15, row=(lane>>4)*4+j)
#pragma unroll
  for (int mi = 0; mi < 4; ++mi) {
#pragma unroll
    for (int j = 0; j < 4; ++j) {
      int lr = mblk * 128 + wr * 64 + mi * 16 + (lane >> 4) * 4 + j;
      if (lr < cnt) {
        size_t slot = (size_t)(seg + lr);
#pragma unroll
        for (int ni = 0; ni < 4; ++ni) {
          float c1v = acc1[mi][ni][j], c3v = acc3[mi][ni][j];
          float sv = c1v / (1.f + __expf(-c1v));
          int f = fBase + wc * 64 + ni * 16 + (lane & 15);
          h[slot * DFF + f] = f2bf(sv * c3v);
        }
      }
    }
  }
}

// ---------------- ffn2: y = wt * (H * W2^T), grouped by expert ----------------
__global__ __launch_bounds__(256, 2) void ffn2_kernel(
    const u16* __restrict__ h, const u16* __restrict__ w2b,
    const int* __restrict__ offs, const float* __restrict__ wt_slot,
    float* __restrict__ y) {
  __shared__ u16 lA[128 * 32];
  __shared__ u16 lB[128 * 32];
  int tid = threadIdx.x, wave = tid >> 6, lane = tid & 63;
  int e = -1, mblk = 0;
  {
    int acc = 0;
    for (int i = 0; i < NE; ++i) {
      int c = offs[i + 1] - offs[i];
      int nb = (c + 127) >> 7;
      if ((int)blockIdx.y < acc + nb) { e = i; mblk = (int)blockIdx.y - acc; break; }
      acc += nb;
    }
  }
  if (e < 0) return;
  int seg = offs[e], cnt = offs[e + 1] - seg;
  int dBase = blockIdx.x * 128;
  int wr = wave >> 1, wc = wave & 1;
  int c0 = 2 * wave, c1 = 2 * wave + 1;
  int rc = lane >> 2, kk = (lane & 3) * 8;
  int lr0 = mblk * 128 + c0 * 16 + rc;
  int lr1 = mblk * 128 + c1 * 16 + rc;
  int sa0 = seg + min(lr0, cnt - 1);
  int sa1 = seg + min(lr1, cnt - 1);
  const u16* gA0 = h + (size_t)sa0 * DFF + kk;
  const u16* gA1 = h + (size_t)sa1 * DFF + kk;
  size_t wbase = (size_t)e * DIM * DFF;
  int d0 = dBase + c0 * 16 + rc, d1 = dBase + c1 * 16 + rc;
  const u16* gB0 = w2b + wbase + (size_t)d0 * DFF + kk;
  const u16* gB1 = w2b + wbase + (size_t)d1 * DFF + kk;

  f32x4 acc[4][4];
#pragma unroll
  for (int i = 0; i < 4; ++i)
#pragma unroll
    for (int j = 0; j < 4; ++j) acc[i][j] = (f32x4){0.f, 0.f, 0.f, 0.f};

  int aBase = (wr * 64 + (lane & 15)) * 32 + (lane >> 4) * 8;
  int bBase = (wc * 64 + (lane & 15)) * 32 + (lane >> 4) * 8;

  for (int k0 = 0; k0 < DFF; k0 += 32) {
    gl_lds16(gA0 + k0, &lA[c0 * 512]);
    gl_lds16(gA1 + k0, &lA[c1 * 512]);
    gl_lds16(gB0 + k0, &lB[c0 * 512]);
    gl_lds16(gB1 + k0, &lB[c1 * 512]);
    __syncthreads();
    bf16x8 af[4], bf[4];
#pragma unroll
    for (int i = 0; i < 4; ++i) {
      af[i] = *(const bf16x8*)&lA[aBase + i * 512];
      bf[i] = *(const bf16x8*)&lB[bBase + i * 512];
    }
#pragma unroll
    for (int mi = 0; mi < 4; ++mi)
#pragma unroll
      for (int ni = 0; ni < 4; ++ni)
        acc[mi][ni] = __builtin_amdgcn_mfma_f32_16x16x32_bf16(af[mi], bf[ni], acc[mi][ni], 0, 0, 0);
    __syncthreads();
  }
#pragma unroll
  for (int mi = 0; mi < 4; ++mi) {
#pragma unroll
    for (int j = 0; j < 4; ++j) {
      int lr = mblk * 128 + wr * 64 + mi * 16 + (lane >> 4) * 4 + j;
      if (lr < cnt) {
        size_t slot = (size_t)(seg + lr);
        float wt = wt_slot[slot];
#pragma unroll
        for (int ni = 0; ni < 4; ++ni) {
          int d = dBase + wc * 64 + ni * 16 + (lane & 15);
          y[slot * DIM + d] = wt * acc[mi][ni][j];
        }
      }
    }
  }
}

// ---------------- combine: out[t] = y[slot0] + y[slot1] ----------------
__global__ __launch_bounds__(256) void combine_kernel(const float* __restrict__ y,
                                                      const int* __restrict__ slot_of,
                                                      float* __restrict__ out) {
  int t = blockIdx.x, dv = threadIdx.x;  // DIM/4 = 256 float4 per token
  int s0 = slot_of[2 * t], s1 = slot_of[2 * t + 1];
  const float4* y4 = (const float4*)y;
  float4 a = y4[(size_t)s0 * 256 + dv];
  float4 b = y4[(size_t)s1 * 256 + dv];
  float4 r; r.x = a.x + b.x; r.y = a.y + b.y; r.z = a.z + b.z; r.w = a.w + b.w;
  ((float4*)out)[(size_t)t * 256 + dv] = r;
}

extern "C" void kernel_launch(void* const* d_in, const int* in_sizes, int n_in,
                              void* d_out, int out_size, void* d_ws, size_t ws_size,
                              hipStream_t stream) {
  const float* x  = (const float*)d_in[0];
  const float* gw = (const float*)d_in[1];
  const float* w1 = (const float*)d_in[2];
  const float* w2 = (const float*)d_in[3];
  const float* w3 = (const float*)d_in[4];
  float* out = (float*)d_out;

  char* ws = (char*)d_ws;
  size_t o = 0;
  u16* xb  = (u16*)(ws + o); o += (size_t)T_TOK * DIM * 2;
  u16* w1b = (u16*)(ws + o); o += (size_t)NE * DFF * DIM * 2;
  u16* w3b = (u16*)(ws + o); o += (size_t)NE * DFF * DIM * 2;
  u16* w2b = (u16*)(ws + o); o += (size_t)NE * DIM * DFF * 2;
  u16* h   = (u16*)(ws + o); o += (size_t)NSLOT * DFF * 2;
  float* y = (float*)(ws + o); o += (size_t)NSLOT * DIM * 4;
  int* idx      = (int*)(ws + o); o += NSLOT * 4;
  float* wts    = (float*)(ws + o); o += NSLOT * 4;
  int* slot_of  = (int*)(ws + o); o += NSLOT * 4;
  int* perm     = (int*)(ws + o); o += NSLOT * 4;
  float* wt_slot= (float*)(ws + o); o += NSLOT * 4;
  int* counts   = (int*)(ws + o); o += 16 * 4;
  int* offs     = (int*)(ws + o); o += 16 * 4;
  int* cursors  = (int*)(ws + o); o += 16 * 4;
  if (o > ws_size) return;  // insufficient workspace -> visible validation failure

  init_kernel<<<1, 64, 0, stream>>>(counts);
  cvt_kernel<<<2048, 256, 0, stream>>>(x,  xb,  (long)T_TOK * DIM);
  cvt_kernel<<<2048, 256, 0, stream>>>(w1, w1b, (long)NE * DFF * DIM);
  cvt_kernel<<<2048, 256, 0, stream>>>(w2, w2b, (long)NE * DIM * DFF);
  cvt_kernel<<<2048, 256, 0, stream>>>(w3, w3b, (long)NE * DFF * DIM);
  gate_kernel<<<T_TOK / 4, 256, 0, stream>>>(x, gw, idx, wts, counts);
  scan_kernel<<<1, 64, 0, stream>>>(counts, offs, cursors);
  scatter_kernel<<<16, 256, 0, stream>>>(idx, wts, cursors, perm, wt_slot, slot_of);
  ffn1_kernel<<<dim3(16, 71), 256, 0, stream>>>(xb, w1b, w3b, offs, perm, h);
  ffn2_kernel<<<dim3(8, 71), 256, 0, stream>>>(h, w2b, offs, wt_slot, y);
  combine_kernel<<<T_TOK, 256, 0, stream>>>(y, slot_of, out);
}

// Round 2
// 365.457 us; speedup vs baseline: 1.0364x; 1.0364x over previous
//
#include <hip/hip_runtime.h>
#include <hip/hip_bf16.h>
#include <cstdint>
#include <cstddef>

#define T_TOK 4096
#define DIM   1024
#define NE    8
#define DFF   2048
#define NSLOT 8192   // T_TOK * TOP_K

typedef __bf16 bf16x8 __attribute__((ext_vector_type(8)));
typedef float  f32x4  __attribute__((ext_vector_type(4)));
typedef unsigned short u16;
typedef unsigned short u16x8 __attribute__((ext_vector_type(8)));

__device__ __forceinline__ u16 f2bf(float f) {
  union { float f; uint32_t u; } v; v.f = f;
  uint32_t r = (v.u + 0x7FFFu + ((v.u >> 16) & 1u)) >> 16;
  return (u16)r;
}

typedef const __attribute__((address_space(1))) uint32_t* gas_ptr;
typedef __attribute__((address_space(3))) uint32_t* las_ptr;
__device__ __forceinline__ void gl_lds16(const void* g, void* l) {
  __builtin_amdgcn_global_load_lds((gas_ptr)g, (las_ptr)l, 16, 0, 0);
}

// ---------------- weight conversion fp32 -> bf16 (w1,w2,w3 in one launch) ----------------
__global__ __launch_bounds__(256) void cvtw_kernel(const float* __restrict__ w1,
                                                   const float* __restrict__ w2,
                                                   const float* __restrict__ w3,
                                                   u16* __restrict__ w1b,
                                                   u16* __restrict__ w2b,
                                                   u16* __restrict__ w3b) {
  const long n = (long)NE * DFF * DIM;
  long stride = (long)gridDim.x * 256 * 8;
  for (long i = ((long)blockIdx.x * 256 + threadIdx.x) * 8; i < 3 * n; i += stride) {
    const float* s; u16* d; long off;
    if (i < n)          { s = w1; d = w1b; off = i; }
    else if (i < 2 * n) { s = w2; d = w2b; off = i - n; }
    else                { s = w3; d = w3b; off = i - 2 * n; }
    float4 a = *(const float4*)(s + off);
    float4 b = *(const float4*)(s + off + 4);
    u16x8 r;
    r[0] = f2bf(a.x); r[1] = f2bf(a.y); r[2] = f2bf(a.z); r[3] = f2bf(a.w);
    r[4] = f2bf(b.x); r[5] = f2bf(b.y); r[6] = f2bf(b.z); r[7] = f2bf(b.w);
    *(u16x8*)(d + off) = r;
  }
}

// ---------------- init ----------------
__global__ void init_kernel(int* counts) {
  if (threadIdx.x < NE) counts[threadIdx.x] = 0;
}

// ---------------- gate: scores fp32, softmax, top-2; also emits xb (bf16 x) ----------------
__global__ __launch_bounds__(256) void gate_kernel(const float* __restrict__ x,
                                                   const float* __restrict__ gw,
                                                   u16* __restrict__ xb,
                                                   int* __restrict__ idx,
                                                   float* __restrict__ wts,
                                                   int* __restrict__ counts) {
  __shared__ float sgw[NE * DIM];
  int tid = threadIdx.x;
  for (int i = tid; i < NE * DIM; i += 256) sgw[i] = gw[i];
  __syncthreads();
  int wave = tid >> 6, lane = tid & 63;
  int t = blockIdx.x * 4 + wave;
  float xv[16];
#pragma unroll
  for (int j = 0; j < 16; ++j) xv[j] = x[(size_t)t * DIM + lane + j * 64];
#pragma unroll
  for (int j = 0; j < 16; ++j) xb[(size_t)t * DIM + lane + j * 64] = f2bf(xv[j]);
  float s[NE];
#pragma unroll
  for (int e = 0; e < NE; ++e) {
    float a = 0.f;
#pragma unroll
    for (int j = 0; j < 16; ++j) a += xv[j] * sgw[e * DIM + lane + j * 64];
    s[e] = a;
  }
#pragma unroll
  for (int off = 32; off > 0; off >>= 1) {
#pragma unroll
    for (int e = 0; e < NE; ++e) s[e] += __shfl_xor(s[e], off, 64);
  }
  if (lane == 0) {
    float m = s[0];
#pragma unroll
    for (int e = 1; e < NE; ++e) m = fmaxf(m, s[e]);
    float p[NE];
#pragma unroll
    for (int e = 0; e < NE; ++e) p[e] = __expf(s[e] - m);
    int i0 = 0;
#pragma unroll
    for (int e = 1; e < NE; ++e) if (s[e] > s[i0]) i0 = e;
    int i1 = (i0 == 0) ? 1 : 0;
#pragma unroll
    for (int e = 0; e < NE; ++e) if (e != i1 && e != i0 && s[e] > s[i1]) i1 = e;
    float p0 = p[i0], p1 = p[i1], inv = 1.f / (p0 + p1);
    idx[2 * t] = i0; idx[2 * t + 1] = i1;
    wts[2 * t] = p0 * inv; wts[2 * t + 1] = p1 * inv;
    atomicAdd(&counts[i0], 1);
    atomicAdd(&counts[i1], 1);
  }
}

// ---------------- scan ----------------
__global__ void scan_kernel(const int* __restrict__ counts, int* __restrict__ offs,
                            int* __restrict__ cursors) {
  if (threadIdx.x == 0) {
    int a = 0;
    for (int e = 0; e < NE; ++e) { offs[e] = a; cursors[e] = a; a += counts[e]; }
    offs[NE] = a;
  }
}

// ---------------- scatter ----------------
__global__ void scatter_kernel(const int* __restrict__ idx, const float* __restrict__ wts,
                               int* __restrict__ cursors, int* __restrict__ perm,
                               float* __restrict__ wt_slot, int* __restrict__ slot_of) {
  int t = blockIdx.x * blockDim.x + threadIdx.x;
  if (t < T_TOK) {
    for (int k = 0; k < 2; ++k) {
      int e = idx[2 * t + k];
      int pos = atomicAdd(&cursors[e], 1);
      perm[pos] = t;
      wt_slot[pos] = wts[2 * t + k];
      slot_of[2 * t + k] = pos;
    }
  }
}

// =====================================================================================
// ffn1: h = silu(X*W1^T) .* (X*W3^T)   BM=256, BN=128, BK=64, 512 thr, 4-phase K-loop
// LDS 128 KiB: A dbuf 2x32KB @0, B1 dbuf 2x16KB @32768(elems), B3 @49152
// Swizzle: chunk (row, j) stored at row-local 16B-slot  pos = j ^ (row&7)
// =====================================================================================
__global__ __launch_bounds__(512, 2) void ffn1_kernel(
    const u16* __restrict__ xb, const u16* __restrict__ w1b, const u16* __restrict__ w3b,
    const int* __restrict__ offs, const int* __restrict__ perm, u16* __restrict__ h) {
  __shared__ u16 smem[65536];
  int tid = threadIdx.x, wave = tid >> 6, lane = tid & 63;
  int wr = wave >> 2, wc = wave & 3;
  int lrow = lane & 15, lq = lane >> 4;
  int e = -1, mblk = 0;
  {
    int acc = 0;
    for (int i = 0; i < NE; ++i) {
      int c = offs[i + 1] - offs[i];
      int nb = (c + 255) >> 8;
      if ((int)blockIdx.y < acc + nb) { e = i; mblk = (int)blockIdx.y - acc; break; }
      acc += nb;
    }
  }
  if (e < 0) return;
  int seg = offs[e], cnt = offs[e + 1] - seg;
  int fBase = blockIdx.x * 128;

  // staging source pointers (pre-swizzled: lane's fixed LDS slot <- matching global chunk)
  const u16* gA[4];
#pragma unroll
  for (int s = 0; s < 4; ++s) {
    int row = s * 64 + wave * 8 + (lane >> 3);
    int j = (lane & 7) ^ (row & 7);
    int r = mblk * 256 + row; if (r > cnt - 1) r = cnt - 1;
    int tok = perm[seg + r];
    gA[s] = xb + (size_t)tok * DIM + j * 8;
  }
  const u16 *gB1[2], *gB3[2];
  size_t wb = (size_t)e * DFF * DIM;
#pragma unroll
  for (int s = 0; s < 2; ++s) {
    int row = s * 64 + wave * 8 + (lane >> 3);
    int j = (lane & 7) ^ (row & 7);
    size_t fb = wb + (size_t)(fBase + row) * DIM + j * 8;
    gB1[s] = w1b + fb;
    gB3[s] = w3b + fb;
  }
  // fragment-read swizzled 16B-slot offsets (row&7 == lane&7 for all frag rows)
  int p8_0 = ((0 | lq) ^ (lane & 7)) * 8;
  int p8_1 = ((4 | lq) ^ (lane & 7)) * 8;

  f32x4 acc1[8][2], acc3[8][2];
#pragma unroll
  for (int i = 0; i < 8; ++i)
#pragma unroll
    for (int j = 0; j < 2; ++j) {
      acc1[i][j] = (f32x4){0.f, 0.f, 0.f, 0.f};
      acc3[i][j] = (f32x4){0.f, 0.f, 0.f, 0.f};
    }

  // prologue: stage K-tile 0 into buf 0
#pragma unroll
  for (int s = 0; s < 4; ++s) gl_lds16(gA[s], &smem[s * 4096 + wave * 512]);
#pragma unroll
  for (int s = 0; s < 2; ++s) gl_lds16(gB1[s], &smem[32768 + s * 4096 + wave * 512]);
#pragma unroll
  for (int s = 0; s < 2; ++s) gl_lds16(gB3[s], &smem[49152 + s * 4096 + wave * 512]);
  asm volatile("s_waitcnt vmcnt(0)" ::: "memory");
  __builtin_amdgcn_s_barrier();

  int wrow = wr * 128 + lrow;
  int brow = wc * 32 + lrow;
  const int NT = DIM / 64;  // 16
  for (int t = 0; t < NT; ++t) {
    int buf = t & 1, nbf = buf ^ 1;
    const u16* lA  = &smem[buf * 16384];
    const u16* lB1 = &smem[32768 + buf * 8192];
    const u16* lB3 = &smem[49152 + buf * 8192];
    int kn = (t + 1) * 64;
    bool pf = (t + 1 < NT);
    bf16x8 b1f0[2], b3f0[2], b1f1[2], b3f1[2];

    // ---- phase 0: rows 0-63 of wave, kk=0 ----
    {
      bf16x8 a[4];
#pragma unroll
      for (int q = 0; q < 4; ++q) a[q] = *(const bf16x8*)&lA[(wrow + q * 16) * 64 + p8_0];
#pragma unroll
      for (int ni = 0; ni < 2; ++ni) {
        b1f0[ni] = *(const bf16x8*)&lB1[(brow + ni * 16) * 64 + p8_0];
        b3f0[ni] = *(const bf16x8*)&lB3[(brow + ni * 16) * 64 + p8_0];
      }
      if (pf) {
        gl_lds16(gA[0] + kn, &smem[nbf * 16384 + 0 * 4096 + wave * 512]);
        gl_lds16(gA[1] + kn, &smem[nbf * 16384 + 1 * 4096 + wave * 512]);
        gl_lds16(gB1[0] + kn, &smem[32768 + nbf * 8192 + 0 * 4096 + wave * 512]);
        gl_lds16(gB1[1] + kn, &smem[32768 + nbf * 8192 + 1 * 4096 + wave * 512]);
      }
      __builtin_amdgcn_s_barrier();
      asm volatile("s_waitcnt lgkmcnt(0)" ::: "memory");
      __builtin_amdgcn_sched_barrier(0);
      __builtin_amdgcn_s_setprio(1);
#pragma unroll
      for (int q = 0; q < 4; ++q)
#pragma unroll
        for (int ni = 0; ni < 2; ++ni) {
          acc1[q][ni] = __builtin_amdgcn_mfma_f32_16x16x32_bf16(a[q], b1f0[ni], acc1[q][ni], 0, 0, 0);
          acc3[q][ni] = __builtin_amdgcn_mfma_f32_16x16x32_bf16(a[q], b3f0[ni], acc3[q][ni], 0, 0, 0);
        }
      __builtin_amdgcn_s_setprio(0);
      __builtin_amdgcn_s_barrier();
    }
    // ---- phase 1: rows 0-63, kk=1 ----
    {
      bf16x8 a[4];
#pragma unroll
      for (int q = 0; q < 4; ++q) a[q] = *(const bf16x8*)&lA[(wrow + q * 16) * 64 + p8_1];
#pragma unroll
      for (int ni = 0; ni < 2; ++ni) {
        b1f1[ni] = *(const bf16x8*)&lB1[(brow + ni * 16) * 64 + p8_1];
        b3f1[ni] = *(const bf16x8*)&lB3[(brow + ni * 16) * 64 + p8_1];
      }
      if (pf) {
        gl_lds16(gA[2] + kn, &smem[nbf * 16384 + 2 * 4096 + wave * 512]);
        gl_lds16(gA[3] + kn, &smem[nbf * 16384 + 3 * 4096 + wave * 512]);
        gl_lds16(gB3[0] + kn, &smem[49152 + nbf * 8192 + 0 * 4096 + wave * 512]);
        gl_lds16(gB3[1] + kn, &smem[49152 + nbf * 8192 + 1 * 4096 + wave * 512]);
      }
      __builtin_amdgcn_s_barrier();
      asm volatile("s_waitcnt lgkmcnt(0)" ::: "memory");
      __builtin_amdgcn_sched_barrier(0);
      __builtin_amdgcn_s_setprio(1);
#pragma unroll
      for (int q = 0; q < 4; ++q)
#pragma unroll
        for (int ni = 0; ni < 2; ++ni) {
          acc1[q][ni] = __builtin_amdgcn_mfma_f32_16x16x32_bf16(a[q], b1f1[ni], acc1[q][ni], 0, 0, 0);
          acc3[q][ni] = __builtin_amdgcn_mfma_f32_16x16x32_bf16(a[q], b3f1[ni], acc3[q][ni], 0, 0, 0);
        }
      __builtin_amdgcn_s_setprio(0);
      __builtin_amdgcn_s_barrier();
    }
    // ---- phase 2: rows 64-127, kk=0 ----
    {
      bf16x8 a[4];
#pragma unroll
      for (int q = 0; q < 4; ++q) a[q] = *(const bf16x8*)&lA[(wrow + 64 + q * 16) * 64 + p8_0];
      __builtin_amdgcn_s_barrier();
      asm volatile("s_waitcnt lgkmcnt(0)" ::: "memory");
      __builtin_amdgcn_sched_barrier(0);
      __builtin_amdgcn_s_setprio(1);
#pragma unroll
      for (int q = 0; q < 4; ++q)
#pragma unroll
        for (int ni = 0; ni < 2; ++ni) {
          acc1[4 + q][ni] = __builtin_amdgcn_mfma_f32_16x16x32_bf16(a[q], b1f0[ni], acc1[4 + q][ni], 0, 0, 0);
          acc3[4 + q][ni] = __builtin_amdgcn_mfma_f32_16x16x32_bf16(a[q], b3f0[ni], acc3[4 + q][ni], 0, 0, 0);
        }
      __builtin_amdgcn_s_setprio(0);
      __builtin_amdgcn_s_barrier();
    }
    // ---- phase 3: rows 64-127, kk=1 ----
    {
      bf16x8 a[4];
#pragma unroll
      for (int q = 0; q < 4; ++q) a[q] = *(const bf16x8*)&lA[(wrow + 64 + q * 16) * 64 + p8_1];
      __builtin_amdgcn_s_barrier();
      asm volatile("s_waitcnt lgkmcnt(0)" ::: "memory");
      __builtin_amdgcn_sched_barrier(0);
      __builtin_amdgcn_s_setprio(1);
#pragma unroll
      for (int q = 0; q < 4; ++q)
#pragma unroll
        for (int ni = 0; ni < 2; ++ni) {
          acc1[4 + q][ni] = __builtin_amdgcn_mfma_f32_16x16x32_bf16(a[q], b1f1[ni], acc1[4 + q][ni], 0, 0, 0);
          acc3[4 + q][ni] = __builtin_amdgcn_mfma_f32_16x16x32_bf16(a[q], b3f1[ni], acc3[4 + q][ni], 0, 0, 0);
        }
      __builtin_amdgcn_s_setprio(0);
      asm volatile("s_waitcnt vmcnt(0)" ::: "memory");
      __builtin_amdgcn_s_barrier();
    }
  }
  // epilogue: silu(c1)*c3 -> h
#pragma unroll
  for (int mi = 0; mi < 8; ++mi) {
#pragma unroll
    for (int jj = 0; jj < 4; ++jj) {
      int lr = mblk * 256 + wr * 128 + mi * 16 + lq * 4 + jj;
      if (lr < cnt) {
        size_t slot = (size_t)(seg + lr);
#pragma unroll
        for (int ni = 0; ni < 2; ++ni) {
          float c1v = acc1[mi][ni][jj], c3v = acc3[mi][ni][jj];
          float sv = c1v / (1.f + __expf(-c1v));
          int f = fBase + wc * 32 + ni * 16 + lrow;
          h[slot * DFF + f] = f2bf(sv * c3v);
        }
      }
    }
  }
}

// =====================================================================================
// ffn2: y = wt * (H * W2^T)   BM=128, BN=128, BK=64, 512 thr, 2-phase K-loop
// LDS 64 KiB: A dbuf 2x16KB @0, B dbuf 2x16KB @16384(elems)  -> 2 blocks/CU
// =====================================================================================
__global__ __launch_bounds__(512, 2) void ffn2_kernel(
    const u16* __restrict__ h, const u16* __restrict__ w2b,
    const int* __restrict__ offs, const float* __restrict__ wt_slot,
    float* __restrict__ y) {
  __shared__ u16 smem[32768];
  int tid = threadIdx.x, wave = tid >> 6, lane = tid & 63;
  int wr = wave >> 2, wc = wave & 3;
  int lrow = lane & 15, lq = lane >> 4;
  int e = -1, mblk = 0;
  {
    int acc = 0;
    for (int i = 0; i < NE; ++i) {
      int c = offs[i + 1] - offs[i];
      int nb = (c + 127) >> 7;
      if ((int)blockIdx.y < acc + nb) { e = i; mblk = (int)blockIdx.y - acc; break; }
      acc += nb;
    }
  }
  if (e < 0) return;
  int seg = offs[e], cnt = offs[e + 1] - seg;
  int dBase = blockIdx.x * 128;

  const u16 *gA[2], *gB[2];
  size_t wb = (size_t)e * DIM * DFF;
#pragma unroll
  for (int s = 0; s < 2; ++s) {
    int row = s * 64 + wave * 8 + (lane >> 3);
    int j = (lane & 7) ^ (row & 7);
    int r = mblk * 128 + row; if (r > cnt - 1) r = cnt - 1;
    gA[s] = h + (size_t)(seg + r) * DFF + j * 8;
    gB[s] = w2b + wb + (size_t)(dBase + row) * DFF + j * 8;
  }
  int p8_0 = ((0 | lq) ^ (lane & 7)) * 8;
  int p8_1 = ((4 | lq) ^ (lane & 7)) * 8;

  f32x4 acc[4][2];
#pragma unroll
  for (int i = 0; i < 4; ++i)
#pragma unroll
    for (int j = 0; j < 2; ++j) acc[i][j] = (f32x4){0.f, 0.f, 0.f, 0.f};

#pragma unroll
  for (int s = 0; s < 2; ++s) gl_lds16(gA[s], &smem[s * 4096 + wave * 512]);
#pragma unroll
  for (int s = 0; s < 2; ++s) gl_lds16(gB[s], &smem[16384 + s * 4096 + wave * 512]);
  asm volatile("s_waitcnt vmcnt(0)" ::: "memory");
  __builtin_amdgcn_s_barrier();

  int wrow = wr * 64 + lrow;
  int brow = wc * 32 + lrow;
  const int NT = DFF / 64;  // 32
  for (int t = 0; t < NT; ++t) {
    int buf = t & 1, nbf = buf ^ 1;
    const u16* lA = &smem[buf * 8192];
    const u16* lB = &smem[16384 + buf * 8192];
    int kn = (t + 1) * 64;
    bool pf = (t + 1 < NT);
    bf16x8 bf0[2], bf1[2];

    // ---- phase 0: kk=0 ----
    {
      bf16x8 a[4];
#pragma unroll
      for (int q = 0; q < 4; ++q) a[q] = *(const bf16x8*)&lA[(wrow + q * 16) * 64 + p8_0];
#pragma unroll
      for (int ni = 0; ni < 2; ++ni) bf0[ni] = *(const bf16x8*)&lB[(brow + ni * 16) * 64 + p8_0];
      if (pf) {
        gl_lds16(gA[0] + kn, &smem[nbf * 8192 + 0 * 4096 + wave * 512]);
        gl_lds16(gA[1] + kn, &smem[nbf * 8192 + 1 * 4096 + wave * 512]);
      }
      __builtin_amdgcn_s_barrier();
      asm volatile("s_waitcnt lgkmcnt(0)" ::: "memory");
      __builtin_amdgcn_sched_barrier(0);
      __builtin_amdgcn_s_setprio(1);
#pragma unroll
      for (int q = 0; q < 4; ++q)
#pragma unroll
        for (int ni = 0; ni < 2; ++ni)
          acc[q][ni] = __builtin_amdgcn_mfma_f32_16x16x32_bf16(a[q], bf0[ni], acc[q][ni], 0, 0, 0);
      __builtin_amdgcn_s_setprio(0);
      __builtin_amdgcn_s_barrier();
    }
    // ---- phase 1: kk=1 ----
    {
      bf16x8 a[4];
#pragma unroll
      for (int q = 0; q < 4; ++q) a[q] = *(const bf16x8*)&lA[(wrow + q * 16) * 64 + p8_1];
#pragma unroll
      for (int ni = 0; ni < 2; ++ni) bf1[ni] = *(const bf16x8*)&lB[(brow + ni * 16) * 64 + p8_1];
      if (pf) {
        gl_lds16(gB[0] + kn, &smem[16384 + nbf * 8192 + 0 * 4096 + wave * 512]);
        gl_lds16(gB[1] + kn, &smem[16384 + nbf * 8192 + 1 * 4096 + wave * 512]);
      }
      __builtin_amdgcn_s_barrier();
      asm volatile("s_waitcnt lgkmcnt(0)" ::: "memory");
      __builtin_amdgcn_sched_barrier(0);
      __builtin_amdgcn_s_setprio(1);
#pragma unroll
      for (int q = 0; q < 4; ++q)
#pragma unroll
        for (int ni = 0; ni < 2; ++ni)
          acc[q][ni] = __builtin_amdgcn_mfma_f32_16x16x32_bf16(a[q], bf1[ni], acc[q][ni], 0, 0, 0);
      __builtin_amdgcn_s_setprio(0);
      asm volatile("s_waitcnt vmcnt(0)" ::: "memory");
      __builtin_amdgcn_s_barrier();
    }
  }
#pragma unroll
  for (int mi = 0; mi < 4; ++mi) {
#pragma unroll
    for (int jj = 0; jj < 4; ++jj) {
      int lr = mblk * 128 + wr * 64 + mi * 16 + lq * 4 + jj;
      if (lr < cnt) {
        size_t slot = (size_t)(seg + lr);
        float wt = wt_slot[slot];
#pragma unroll
        for (int ni = 0; ni < 2; ++ni) {
          int d = dBase + wc * 32 + ni * 16 + lrow;
          y[slot * DIM + d] = wt * acc[mi][ni][jj];
        }
      }
    }
  }
}

// ---------------- combine: out[t] = y[slot0] + y[slot1] ----------------
__global__ __launch_bounds__(256) void combine_kernel(const float* __restrict__ y,
                                                      const int* __restrict__ slot_of,
                                                      float* __restrict__ out) {
  int t = blockIdx.x, dv = threadIdx.x;
  int s0 = slot_of[2 * t], s1 = slot_of[2 * t + 1];
  const float4* y4 = (const float4*)y;
  float4 a = y4[(size_t)s0 * 256 + dv];
  float4 b = y4[(size_t)s1 * 256 + dv];
  float4 r; r.x = a.x + b.x; r.y = a.y + b.y; r.z = a.z + b.z; r.w = a.w + b.w;
  ((float4*)out)[(size_t)t * 256 + dv] = r;
}

extern "C" void kernel_launch(void* const* d_in, const int* in_sizes, int n_in,
                              void* d_out, int out_size, void* d_ws, size_t ws_size,
                              hipStream_t stream) {
  const float* x  = (const float*)d_in[0];
  const float* gw = (const float*)d_in[1];
  const float* w1 = (const float*)d_in[2];
  const float* w2 = (const float*)d_in[3];
  const float* w3 = (const float*)d_in[4];
  float* out = (float*)d_out;

  char* ws = (char*)d_ws;
  size_t o = 0;
  u16* xb  = (u16*)(ws + o); o += (size_t)T_TOK * DIM * 2;
  u16* w1b = (u16*)(ws + o); o += (size_t)NE * DFF * DIM * 2;
  u16* w3b = (u16*)(ws + o); o += (size_t)NE * DFF * DIM * 2;
  u16* w2b = (u16*)(ws + o); o += (size_t)NE * DIM * DFF * 2;
  u16* h   = (u16*)(ws + o); o += (size_t)NSLOT * DFF * 2;
  float* y = (float*)(ws + o); o += (size_t)NSLOT * DIM * 4;
  int* idx      = (int*)(ws + o); o += NSLOT * 4;
  float* wts    = (float*)(ws + o); o += NSLOT * 4;
  int* slot_of  = (int*)(ws + o); o += NSLOT * 4;
  int* perm     = (int*)(ws + o); o += NSLOT * 4;
  float* wt_slot= (float*)(ws + o); o += NSLOT * 4;
  int* counts   = (int*)(ws + o); o += 16 * 4;
  int* offs     = (int*)(ws + o); o += 16 * 4;
  int* cursors  = (int*)(ws + o); o += 16 * 4;
  if (o > ws_size) return;

  init_kernel<<<1, 64, 0, stream>>>(counts);
  cvtw_kernel<<<2048, 256, 0, stream>>>(w1, w2, w3, w1b, w2b, w3b);
  gate_kernel<<<T_TOK / 4, 256, 0, stream>>>(x, gw, xb, idx, wts, counts);
  scan_kernel<<<1, 64, 0, stream>>>(counts, offs, cursors);
  scatter_kernel<<<16, 256, 0, stream>>>(idx, wts, cursors, perm, wt_slot, slot_of);
  ffn1_kernel<<<dim3(16, 40), 512, 0, stream>>>(xb, w1b, w3b, offs, perm, h);
  ffn2_kernel<<<dim3(8, 71), 512, 0, stream>>>(h, w2b, offs, wt_slot, y);
  combine_kernel<<<T_TOK, 256, 0, stream>>>(y, slot_of, out);
}

// Round 3
// 340.431 us; speedup vs baseline: 1.1126x; 1.0735x over previous
//
#include <hip/hip_runtime.h>
#include <hip/hip_bf16.h>
#include <cstdint>
#include <cstddef>

#define T_TOK 4096
#define DIM   1024
#define NE    8
#define DFF   2048
#define NSLOT 8192   // T_TOK * TOP_K

typedef __bf16 bf16x8 __attribute__((ext_vector_type(8)));
typedef float  f32x4  __attribute__((ext_vector_type(4)));
typedef unsigned short u16;
typedef unsigned short u16x8 __attribute__((ext_vector_type(8)));

__device__ __forceinline__ u16 f2bf(float f) {
  union { float f; uint32_t u; } v; v.f = f;
  uint32_t r = (v.u + 0x7FFFu + ((v.u >> 16) & 1u)) >> 16;
  return (u16)r;
}

typedef const __attribute__((address_space(1))) uint32_t* gas_ptr;
typedef __attribute__((address_space(3))) uint32_t* las_ptr;
__device__ __forceinline__ void gl_lds16(const void* g, void* l) {
  __builtin_amdgcn_global_load_lds((gas_ptr)g, (las_ptr)l, 16, 0, 0);
}

// ---------------- weight conversion fp32 -> bf16 (w1,w2,w3) + counts init ----------------
__global__ __launch_bounds__(256) void cvtw_kernel(const float* __restrict__ w1,
                                                   const float* __restrict__ w2,
                                                   const float* __restrict__ w3,
                                                   u16* __restrict__ w1b,
                                                   u16* __restrict__ w2b,
                                                   u16* __restrict__ w3b,
                                                   int* __restrict__ counts) {
  if (blockIdx.x == 0 && threadIdx.x < NE) counts[threadIdx.x] = 0;
  const long n = (long)NE * DFF * DIM;
  long stride = (long)gridDim.x * 256 * 8;
  for (long i = ((long)blockIdx.x * 256 + threadIdx.x) * 8; i < 3 * n; i += stride) {
    const float* s; u16* d; long off;
    if (i < n)          { s = w1; d = w1b; off = i; }
    else if (i < 2 * n) { s = w2; d = w2b; off = i - n; }
    else                { s = w3; d = w3b; off = i - 2 * n; }
    float4 a = *(const float4*)(s + off);
    float4 b = *(const float4*)(s + off + 4);
    u16x8 r;
    r[0] = f2bf(a.x); r[1] = f2bf(a.y); r[2] = f2bf(a.z); r[3] = f2bf(a.w);
    r[4] = f2bf(b.x); r[5] = f2bf(b.y); r[6] = f2bf(b.z); r[7] = f2bf(b.w);
    *(u16x8*)(d + off) = r;
  }
}

// ---------------- gate: scores fp32, softmax, top-2; also emits xb (bf16 x) ----------------
__global__ __launch_bounds__(256) void gate_kernel(const float* __restrict__ x,
                                                   const float* __restrict__ gw,
                                                   u16* __restrict__ xb,
                                                   int* __restrict__ idx,
                                                   float* __restrict__ wts,
                                                   int* __restrict__ counts) {
  __shared__ float sgw[NE * DIM];
  int tid = threadIdx.x;
  for (int i = tid; i < NE * DIM; i += 256) sgw[i] = gw[i];
  __syncthreads();
  int wave = tid >> 6, lane = tid & 63;
  int t = blockIdx.x * 4 + wave;
  float xv[16];
#pragma unroll
  for (int j = 0; j < 16; ++j) xv[j] = x[(size_t)t * DIM + lane + j * 64];
#pragma unroll
  for (int j = 0; j < 16; ++j) xb[(size_t)t * DIM + lane + j * 64] = f2bf(xv[j]);
  float s[NE];
#pragma unroll
  for (int e = 0; e < NE; ++e) {
    float a = 0.f;
#pragma unroll
    for (int j = 0; j < 16; ++j) a += xv[j] * sgw[e * DIM + lane + j * 64];
    s[e] = a;
  }
#pragma unroll
  for (int off = 32; off > 0; off >>= 1) {
#pragma unroll
    for (int e = 0; e < NE; ++e) s[e] += __shfl_xor(s[e], off, 64);
  }
  if (lane == 0) {
    float m = s[0];
#pragma unroll
    for (int e = 1; e < NE; ++e) m = fmaxf(m, s[e]);
    float p[NE];
#pragma unroll
    for (int e = 0; e < NE; ++e) p[e] = __expf(s[e] - m);
    int i0 = 0;
#pragma unroll
    for (int e = 1; e < NE; ++e) if (s[e] > s[i0]) i0 = e;
    int i1 = (i0 == 0) ? 1 : 0;
#pragma unroll
    for (int e = 0; e < NE; ++e) if (e != i1 && e != i0 && s[e] > s[i1]) i1 = e;
    float p0 = p[i0], p1 = p[i1], inv = 1.f / (p0 + p1);
    idx[2 * t] = i0; idx[2 * t + 1] = i1;
    wts[2 * t] = p0 * inv; wts[2 * t + 1] = p1 * inv;
    atomicAdd(&counts[i0], 1);
    atomicAdd(&counts[i1], 1);
  }
}

// ---------------- fused scan + scatter (single block) ----------------
__global__ __launch_bounds__(1024) void scan_scatter_kernel(
    const int* __restrict__ counts, const int* __restrict__ idx,
    const float* __restrict__ wts, int* __restrict__ offs,
    int* __restrict__ perm, float* __restrict__ wt_slot, int* __restrict__ slot_of) {
  __shared__ int scur[NE];
  __shared__ int soff[NE + 1];
  if (threadIdx.x == 0) {
    int a = 0;
    for (int e = 0; e < NE; ++e) { soff[e] = a; scur[e] = a; a += counts[e]; }
    soff[NE] = a;
  }
  __syncthreads();
  if (threadIdx.x < NE + 1) offs[threadIdx.x] = soff[threadIdx.x];
  for (int t = threadIdx.x; t < T_TOK; t += 1024) {
    for (int k = 0; k < 2; ++k) {
      int e = idx[2 * t + k];
      int pos = atomicAdd(&scur[e], 1);
      perm[pos] = t;
      wt_slot[pos] = wts[2 * t + k];
      slot_of[2 * t + k] = pos;
    }
  }
}

// =====================================================================================
// ffn1: h = silu(X*W1^T) .* (X*W3^T)   BM=256, BN=128, BK=64, 512 thr, 4-phase K-loop
// 2-deep counted-vmcnt pipeline: tile t+2 issued at boundary of t, vmcnt(8) waits t+1.
// LDS 128 KiB: A dbuf 2x32KB @0, B1 dbuf 2x16KB @32768(elems), B3 @49152
// Swizzle: chunk (row, j) stored at row-local 16B-slot  pos = j ^ (row&7)
// =====================================================================================
__global__ __launch_bounds__(512, 2) void ffn1_kernel(
    const u16* __restrict__ xb, const u16* __restrict__ w1b, const u16* __restrict__ w3b,
    const int* __restrict__ offs, const int* __restrict__ perm, u16* __restrict__ h) {
  __shared__ u16 smem[65536];
  int tid = threadIdx.x, wave = tid >> 6, lane = tid & 63;
  int wr = wave >> 2, wc = wave & 3;
  int lrow = lane & 15, lq = lane >> 4;
  int e = -1, mblk = 0;
  {
    int acc = 0;
    for (int i = 0; i < NE; ++i) {
      int c = offs[i + 1] - offs[i];
      int nb = (c + 255) >> 8;
      if ((int)blockIdx.y < acc + nb) { e = i; mblk = (int)blockIdx.y - acc; break; }
      acc += nb;
    }
  }
  if (e < 0) return;
  int seg = offs[e], cnt = offs[e + 1] - seg;
  int fBase = blockIdx.x * 128;

  const u16* gA[4];
#pragma unroll
  for (int s = 0; s < 4; ++s) {
    int row = s * 64 + wave * 8 + (lane >> 3);
    int j = (lane & 7) ^ (row & 7);
    int r = mblk * 256 + row; if (r > cnt - 1) r = cnt - 1;
    int tok = perm[seg + r];
    gA[s] = xb + (size_t)tok * DIM + j * 8;
  }
  const u16 *gB1[2], *gB3[2];
  size_t wb = (size_t)e * DFF * DIM;
#pragma unroll
  for (int s = 0; s < 2; ++s) {
    int row = s * 64 + wave * 8 + (lane >> 3);
    int j = (lane & 7) ^ (row & 7);
    size_t fb = wb + (size_t)(fBase + row) * DIM + j * 8;
    gB1[s] = w1b + fb;
    gB3[s] = w3b + fb;
  }
  int p8_0 = ((0 | lq) ^ (lane & 7)) * 8;
  int p8_1 = ((4 | lq) ^ (lane & 7)) * 8;

  f32x4 acc1[8][2], acc3[8][2];
#pragma unroll
  for (int i = 0; i < 8; ++i)
#pragma unroll
    for (int j = 0; j < 2; ++j) {
      acc1[i][j] = (f32x4){0.f, 0.f, 0.f, 0.f};
      acc3[i][j] = (f32x4){0.f, 0.f, 0.f, 0.f};
    }

  // stage one K-tile (8 gl_lds per wave) into buffer b
#define STAGE1(kt, b)                                                                   \
  do {                                                                                  \
    int kb = (kt) * 64;                                                                 \
    gl_lds16(gA[0] + kb, &smem[(b) * 16384 + 0 * 4096 + wave * 512]);                   \
    gl_lds16(gA[1] + kb, &smem[(b) * 16384 + 1 * 4096 + wave * 512]);                   \
    gl_lds16(gA[2] + kb, &smem[(b) * 16384 + 2 * 4096 + wave * 512]);                   \
    gl_lds16(gA[3] + kb, &smem[(b) * 16384 + 3 * 4096 + wave * 512]);                   \
    gl_lds16(gB1[0] + kb, &smem[32768 + (b) * 8192 + 0 * 4096 + wave * 512]);           \
    gl_lds16(gB1[1] + kb, &smem[32768 + (b) * 8192 + 1 * 4096 + wave * 512]);           \
    gl_lds16(gB3[0] + kb, &smem[49152 + (b) * 8192 + 0 * 4096 + wave * 512]);           \
    gl_lds16(gB3[1] + kb, &smem[49152 + (b) * 8192 + 1 * 4096 + wave * 512]);           \
  } while (0)

  // prologue: 2 tiles in flight
  STAGE1(0, 0);
  STAGE1(1, 1);
  asm volatile("s_waitcnt vmcnt(8)" ::: "memory");
  __builtin_amdgcn_s_barrier();

  int wrow = wr * 128 + lrow;
  int brow = wc * 32 + lrow;
  const int NT = DIM / 64;  // 16
  for (int t = 0; t < NT; ++t) {
    int buf = t & 1;
    const u16* lA  = &smem[buf * 16384];
    const u16* lB1 = &smem[32768 + buf * 8192];
    const u16* lB3 = &smem[49152 + buf * 8192];
    bf16x8 b1f0[2], b3f0[2], b1f1[2], b3f1[2];

    // ---- phase 0: rows 0-63 of wave, kk=0 ----
    {
      bf16x8 a[4];
#pragma unroll
      for (int q = 0; q < 4; ++q) a[q] = *(const bf16x8*)&lA[(wrow + q * 16) * 64 + p8_0];
#pragma unroll
      for (int ni = 0; ni < 2; ++ni) {
        b1f0[ni] = *(const bf16x8*)&lB1[(brow + ni * 16) * 64 + p8_0];
        b3f0[ni] = *(const bf16x8*)&lB3[(brow + ni * 16) * 64 + p8_0];
      }
      __builtin_amdgcn_s_barrier();
      asm volatile("s_waitcnt lgkmcnt(0)" ::: "memory");
      __builtin_amdgcn_sched_barrier(0);
      __builtin_amdgcn_s_setprio(1);
#pragma unroll
      for (int q = 0; q < 4; ++q)
#pragma unroll
        for (int ni = 0; ni < 2; ++ni) {
          acc1[q][ni] = __builtin_amdgcn_mfma_f32_16x16x32_bf16(a[q], b1f0[ni], acc1[q][ni], 0, 0, 0);
          acc3[q][ni] = __builtin_amdgcn_mfma_f32_16x16x32_bf16(a[q], b3f0[ni], acc3[q][ni], 0, 0, 0);
        }
      __builtin_amdgcn_s_setprio(0);
      __builtin_amdgcn_s_barrier();
    }
    // ---- phase 1: rows 0-63, kk=1 ----
    {
      bf16x8 a[4];
#pragma unroll
      for (int q = 0; q < 4; ++q) a[q] = *(const bf16x8*)&lA[(wrow + q * 16) * 64 + p8_1];
#pragma unroll
      for (int ni = 0; ni < 2; ++ni) {
        b1f1[ni] = *(const bf16x8*)&lB1[(brow + ni * 16) * 64 + p8_1];
        b3f1[ni] = *(const bf16x8*)&lB3[(brow + ni * 16) * 64 + p8_1];
      }
      __builtin_amdgcn_s_barrier();
      asm volatile("s_waitcnt lgkmcnt(0)" ::: "memory");
      __builtin_amdgcn_sched_barrier(0);
      __builtin_amdgcn_s_setprio(1);
#pragma unroll
      for (int q = 0; q < 4; ++q)
#pragma unroll
        for (int ni = 0; ni < 2; ++ni) {
          acc1[q][ni] = __builtin_amdgcn_mfma_f32_16x16x32_bf16(a[q], b1f1[ni], acc1[q][ni], 0, 0, 0);
          acc3[q][ni] = __builtin_amdgcn_mfma_f32_16x16x32_bf16(a[q], b3f1[ni], acc3[q][ni], 0, 0, 0);
        }
      __builtin_amdgcn_s_setprio(0);
      __builtin_amdgcn_s_barrier();
    }
    // ---- phase 2: rows 64-127, kk=0 ----
    {
      bf16x8 a[4];
#pragma unroll
      for (int q = 0; q < 4; ++q) a[q] = *(const bf16x8*)&lA[(wrow + 64 + q * 16) * 64 + p8_0];
      __builtin_amdgcn_s_barrier();
      asm volatile("s_waitcnt lgkmcnt(0)" ::: "memory");
      __builtin_amdgcn_sched_barrier(0);
      __builtin_amdgcn_s_setprio(1);
#pragma unroll
      for (int q = 0; q < 4; ++q)
#pragma unroll
        for (int ni = 0; ni < 2; ++ni) {
          acc1[4 + q][ni] = __builtin_amdgcn_mfma_f32_16x16x32_bf16(a[q], b1f0[ni], acc1[4 + q][ni], 0, 0, 0);
          acc3[4 + q][ni] = __builtin_amdgcn_mfma_f32_16x16x32_bf16(a[q], b3f0[ni], acc3[4 + q][ni], 0, 0, 0);
        }
      __builtin_amdgcn_s_setprio(0);
      __builtin_amdgcn_s_barrier();
    }
    // ---- phase 3: rows 64-127, kk=1 ----
    {
      bf16x8 a[4];
#pragma unroll
      for (int q = 0; q < 4; ++q) a[q] = *(const bf16x8*)&lA[(wrow + 64 + q * 16) * 64 + p8_1];
      __builtin_amdgcn_s_barrier();
      asm volatile("s_waitcnt lgkmcnt(0)" ::: "memory");
      __builtin_amdgcn_sched_barrier(0);
      __builtin_amdgcn_s_setprio(1);
#pragma unroll
      for (int q = 0; q < 4; ++q)
#pragma unroll
        for (int ni = 0; ni < 2; ++ni) {
          acc1[4 + q][ni] = __builtin_amdgcn_mfma_f32_16x16x32_bf16(a[q], b1f1[ni], acc1[4 + q][ni], 0, 0, 0);
          acc3[4 + q][ni] = __builtin_amdgcn_mfma_f32_16x16x32_bf16(a[q], b3f1[ni], acc3[4 + q][ni], 0, 0, 0);
        }
      __builtin_amdgcn_s_setprio(0);
      __builtin_amdgcn_s_barrier();
    }
    // ---- tile boundary: issue t+2 into just-consumed buf, wait only on t+1 ----
    if (t + 2 < NT) {
      STAGE1(t + 2, buf);
      asm volatile("s_waitcnt vmcnt(8)" ::: "memory");
      __builtin_amdgcn_s_barrier();
    } else if (t + 1 < NT) {
      asm volatile("s_waitcnt vmcnt(0)" ::: "memory");
      __builtin_amdgcn_s_barrier();
    }
  }
#undef STAGE1
  // epilogue: silu(c1)*c3 -> h
#pragma unroll
  for (int mi = 0; mi < 8; ++mi) {
#pragma unroll
    for (int jj = 0; jj < 4; ++jj) {
      int lr = mblk * 256 + wr * 128 + mi * 16 + lq * 4 + jj;
      if (lr < cnt) {
        size_t slot = (size_t)(seg + lr);
#pragma unroll
        for (int ni = 0; ni < 2; ++ni) {
          float c1v = acc1[mi][ni][jj], c3v = acc3[mi][ni][jj];
          float sv = c1v / (1.f + __expf(-c1v));
          int f = fBase + wc * 32 + ni * 16 + lrow;
          h[slot * DFF + f] = f2bf(sv * c3v);
        }
      }
    }
  }
}

// =====================================================================================
// ffn2: y = wt * (H * W2^T)   BM=128, BN=128, BK=64, 512 thr, 2-phase K-loop
// 2-deep counted-vmcnt pipeline (vmcnt(4)).  LDS 64 KiB -> 2 blocks/CU.
// =====================================================================================
__global__ __launch_bounds__(512, 2) void ffn2_kernel(
    const u16* __restrict__ h, const u16* __restrict__ w2b,
    const int* __restrict__ offs, const float* __restrict__ wt_slot,
    float* __restrict__ y) {
  __shared__ u16 smem[32768];
  int tid = threadIdx.x, wave = tid >> 6, lane = tid & 63;
  int wr = wave >> 2, wc = wave & 3;
  int lrow = lane & 15, lq = lane >> 4;
  int e = -1, mblk = 0;
  {
    int acc = 0;
    for (int i = 0; i < NE; ++i) {
      int c = offs[i + 1] - offs[i];
      int nb = (c + 127) >> 7;
      if ((int)blockIdx.y < acc + nb) { e = i; mblk = (int)blockIdx.y - acc; break; }
      acc += nb;
    }
  }
  if (e < 0) return;
  int seg = offs[e], cnt = offs[e + 1] - seg;
  int dBase = blockIdx.x * 128;

  const u16 *gA[2], *gB[2];
  size_t wb = (size_t)e * DIM * DFF;
#pragma unroll
  for (int s = 0; s < 2; ++s) {
    int row = s * 64 + wave * 8 + (lane >> 3);
    int j = (lane & 7) ^ (row & 7);
    int r = mblk * 128 + row; if (r > cnt - 1) r = cnt - 1;
    gA[s] = h + (size_t)(seg + r) * DFF + j * 8;
    gB[s] = w2b + wb + (size_t)(dBase + row) * DFF + j * 8;
  }
  int p8_0 = ((0 | lq) ^ (lane & 7)) * 8;
  int p8_1 = ((4 | lq) ^ (lane & 7)) * 8;

  f32x4 acc[4][2];
#pragma unroll
  for (int i = 0; i < 4; ++i)
#pragma unroll
    for (int j = 0; j < 2; ++j) acc[i][j] = (f32x4){0.f, 0.f, 0.f, 0.f};

#define STAGE2(kt, b)                                                                 \
  do {                                                                                \
    int kb = (kt) * 64;                                                               \
    gl_lds16(gA[0] + kb, &smem[(b) * 8192 + 0 * 4096 + wave * 512]);                  \
    gl_lds16(gA[1] + kb, &smem[(b) * 8192 + 1 * 4096 + wave * 512]);                  \
    gl_lds16(gB[0] + kb, &smem[16384 + (b) * 8192 + 0 * 4096 + wave * 512]);          \
    gl_lds16(gB[1] + kb, &smem[16384 + (b) * 8192 + 1 * 4096 + wave * 512]);          \
  } while (0)

  STAGE2(0, 0);
  STAGE2(1, 1);
  asm volatile("s_waitcnt vmcnt(4)" ::: "memory");
  __builtin_amdgcn_s_barrier();

  int wrow = wr * 64 + lrow;
  int brow = wc * 32 + lrow;
  const int NT = DFF / 64;  // 32
  for (int t = 0; t < NT; ++t) {
    int buf = t & 1;
    const u16* lA = &smem[buf * 8192];
    const u16* lB = &smem[16384 + buf * 8192];
    bf16x8 bf0[2], bf1[2];

    // ---- phase 0: kk=0 ----
    {
      bf16x8 a[4];
#pragma unroll
      for (int q = 0; q < 4; ++q) a[q] = *(const bf16x8*)&lA[(wrow + q * 16) * 64 + p8_0];
#pragma unroll
      for (int ni = 0; ni < 2; ++ni) bf0[ni] = *(const bf16x8*)&lB[(brow + ni * 16) * 64 + p8_0];
      __builtin_amdgcn_s_barrier();
      asm volatile("s_waitcnt lgkmcnt(0)" ::: "memory");
      __builtin_amdgcn_sched_barrier(0);
      __builtin_amdgcn_s_setprio(1);
#pragma unroll
      for (int q = 0; q < 4; ++q)
#pragma unroll
        for (int ni = 0; ni < 2; ++ni)
          acc[q][ni] = __builtin_amdgcn_mfma_f32_16x16x32_bf16(a[q], bf0[ni], acc[q][ni], 0, 0, 0);
      __builtin_amdgcn_s_setprio(0);
      __builtin_amdgcn_s_barrier();
    }
    // ---- phase 1: kk=1 ----
    {
      bf16x8 a[4];
#pragma unroll
      for (int q = 0; q < 4; ++q) a[q] = *(const bf16x8*)&lA[(wrow + q * 16) * 64 + p8_1];
#pragma unroll
      for (int ni = 0; ni < 2; ++ni) bf1[ni] = *(const bf16x8*)&lB[(brow + ni * 16) * 64 + p8_1];
      __builtin_amdgcn_s_barrier();
      asm volatile("s_waitcnt lgkmcnt(0)" ::: "memory");
      __builtin_amdgcn_sched_barrier(0);
      __builtin_amdgcn_s_setprio(1);
#pragma unroll
      for (int q = 0; q < 4; ++q)
#pragma unroll
        for (int ni = 0; ni < 2; ++ni)
          acc[q][ni] = __builtin_amdgcn_mfma_f32_16x16x32_bf16(a[q], bf1[ni], acc[q][ni], 0, 0, 0);
      __builtin_amdgcn_s_setprio(0);
      __builtin_amdgcn_s_barrier();
    }
    // ---- tile boundary ----
    if (t + 2 < NT) {
      STAGE2(t + 2, buf);
      asm volatile("s_waitcnt vmcnt(4)" ::: "memory");
      __builtin_amdgcn_s_barrier();
    } else if (t + 1 < NT) {
      asm volatile("s_waitcnt vmcnt(0)" ::: "memory");
      __builtin_amdgcn_s_barrier();
    }
  }
#undef STAGE2
#pragma unroll
  for (int mi = 0; mi < 4; ++mi) {
#pragma unroll
    for (int jj = 0; jj < 4; ++jj) {
      int lr = mblk * 128 + wr * 64 + mi * 16 + lq * 4 + jj;
      if (lr < cnt) {
        size_t slot = (size_t)(seg + lr);
        float wt = wt_slot[slot];
#pragma unroll
        for (int ni = 0; ni < 2; ++ni) {
          int d = dBase + wc * 32 + ni * 16 + lrow;
          y[slot * DIM + d] = wt * acc[mi][ni][jj];
        }
      }
    }
  }
}

// ---------------- combine: out[t] = y[slot0] + y[slot1] ----------------
__global__ __launch_bounds__(256) void combine_kernel(const float* __restrict__ y,
                                                      const int* __restrict__ slot_of,
                                                      float* __restrict__ out) {
  int t = blockIdx.x, dv = threadIdx.x;
  int s0 = slot_of[2 * t], s1 = slot_of[2 * t + 1];
  const float4* y4 = (const float4*)y;
  float4 a = y4[(size_t)s0 * 256 + dv];
  float4 b = y4[(size_t)s1 * 256 + dv];
  float4 r; r.x = a.x + b.x; r.y = a.y + b.y; r.z = a.z + b.z; r.w = a.w + b.w;
  ((float4*)out)[(size_t)t * 256 + dv] = r;
}

extern "C" void kernel_launch(void* const* d_in, const int* in_sizes, int n_in,
                              void* d_out, int out_size, void* d_ws, size_t ws_size,
                              hipStream_t stream) {
  const float* x  = (const float*)d_in[0];
  const float* gw = (const float*)d_in[1];
  const float* w1 = (const float*)d_in[2];
  const float* w2 = (const float*)d_in[3];
  const float* w3 = (const float*)d_in[4];
  float* out = (float*)d_out;

  char* ws = (char*)d_ws;
  size_t o = 0;
  u16* xb  = (u16*)(ws + o); o += (size_t)T_TOK * DIM * 2;
  u16* w1b = (u16*)(ws + o); o += (size_t)NE * DFF * DIM * 2;
  u16* w3b = (u16*)(ws + o); o += (size_t)NE * DFF * DIM * 2;
  u16* w2b = (u16*)(ws + o); o += (size_t)NE * DIM * DFF * 2;
  u16* h   = (u16*)(ws + o); o += (size_t)NSLOT * DFF * 2;
  float* y = (float*)(ws + o); o += (size_t)NSLOT * DIM * 4;
  int* idx      = (int*)(ws + o); o += NSLOT * 4;
  float* wts    = (float*)(ws + o); o += NSLOT * 4;
  int* slot_of  = (int*)(ws + o); o += NSLOT * 4;
  int* perm     = (int*)(ws + o); o += NSLOT * 4;
  float* wt_slot= (float*)(ws + o); o += NSLOT * 4;
  int* counts   = (int*)(ws + o); o += 16 * 4;
  int* offs     = (int*)(ws + o); o += 16 * 4;
  if (o > ws_size) return;

  cvtw_kernel<<<2048, 256, 0, stream>>>(w1, w2, w3, w1b, w2b, w3b, counts);
  gate_kernel<<<T_TOK / 4, 256, 0, stream>>>(x, gw, xb, idx, wts, counts);
  scan_scatter_kernel<<<1, 1024, 0, stream>>>(counts, idx, wts, offs, perm, wt_slot, slot_of);
  ffn1_kernel<<<dim3(16, 40), 512, 0, stream>>>(xb, w1b, w3b, offs, perm, h);
  ffn2_kernel<<<dim3(8, 71), 512, 0, stream>>>(h, w2b, offs, wt_slot, y);
  combine_kernel<<<T_TOK, 256, 0, stream>>>(y, slot_of, out);
}

// Round 4
// 338.381 us; speedup vs baseline: 1.1193x; 1.0061x over previous
//
#include <hip/hip_runtime.h>
#include <hip/hip_bf16.h>
#include <cstdint>
#include <cstddef>

#define T_TOK 4096
#define DIM   1024
#define NE    8
#define DFF   2048
#define NSLOT 8192   // T_TOK * TOP_K

typedef __bf16 bf16x8 __attribute__((ext_vector_type(8)));
typedef float  f32x4  __attribute__((ext_vector_type(4)));
typedef unsigned short u16;
typedef unsigned short u16x8 __attribute__((ext_vector_type(8)));

__device__ __forceinline__ u16 f2bf(float f) {
  union { float f; uint32_t u; } v; v.f = f;
  uint32_t r = (v.u + 0x7FFFu + ((v.u >> 16) & 1u)) >> 16;
  return (u16)r;
}

typedef const __attribute__((address_space(1))) uint32_t* gas_ptr;
typedef __attribute__((address_space(3))) uint32_t* las_ptr;
__device__ __forceinline__ void gl_lds16(const void* g, void* l) {
  __builtin_amdgcn_global_load_lds((gas_ptr)g, (las_ptr)l, 16, 0, 0);
}

// ---------------- weight conversion fp32 -> bf16 (w1,w2,w3) + counts init ----------------
__global__ __launch_bounds__(256) void cvtw_kernel(const float* __restrict__ w1,
                                                   const float* __restrict__ w2,
                                                   const float* __restrict__ w3,
                                                   u16* __restrict__ w1b,
                                                   u16* __restrict__ w2b,
                                                   u16* __restrict__ w3b,
                                                   int* __restrict__ counts) {
  if (blockIdx.x == 0 && threadIdx.x < NE) counts[threadIdx.x] = 0;
  const long n = (long)NE * DFF * DIM;
  long stride = (long)gridDim.x * 256 * 8;
  for (long i = ((long)blockIdx.x * 256 + threadIdx.x) * 8; i < 3 * n; i += stride) {
    const float* s; u16* d; long off;
    if (i < n)          { s = w1; d = w1b; off = i; }
    else if (i < 2 * n) { s = w2; d = w2b; off = i - n; }
    else                { s = w3; d = w3b; off = i - 2 * n; }
    float4 a = *(const float4*)(s + off);
    float4 b = *(const float4*)(s + off + 4);
    u16x8 r;
    r[0] = f2bf(a.x); r[1] = f2bf(a.y); r[2] = f2bf(a.z); r[3] = f2bf(a.w);
    r[4] = f2bf(b.x); r[5] = f2bf(b.y); r[6] = f2bf(b.z); r[7] = f2bf(b.w);
    *(u16x8*)(d + off) = r;
  }
}

// ---------------- gate: scores fp32, softmax, top-2; also emits xb (bf16 x) ----------------
__global__ __launch_bounds__(256) void gate_kernel(const float* __restrict__ x,
                                                   const float* __restrict__ gw,
                                                   u16* __restrict__ xb,
                                                   int* __restrict__ idx,
                                                   float* __restrict__ wts,
                                                   int* __restrict__ counts) {
  __shared__ float sgw[NE * DIM];
  int tid = threadIdx.x;
  for (int i = tid; i < NE * DIM; i += 256) sgw[i] = gw[i];
  __syncthreads();
  int wave = tid >> 6, lane = tid & 63;
  int t = blockIdx.x * 4 + wave;
  float xv[16];
#pragma unroll
  for (int j = 0; j < 16; ++j) xv[j] = x[(size_t)t * DIM + lane + j * 64];
#pragma unroll
  for (int j = 0; j < 16; ++j) xb[(size_t)t * DIM + lane + j * 64] = f2bf(xv[j]);
  float s[NE];
#pragma unroll
  for (int e = 0; e < NE; ++e) {
    float a = 0.f;
#pragma unroll
    for (int j = 0; j < 16; ++j) a += xv[j] * sgw[e * DIM + lane + j * 64];
    s[e] = a;
  }
#pragma unroll
  for (int off = 32; off > 0; off >>= 1) {
#pragma unroll
    for (int e = 0; e < NE; ++e) s[e] += __shfl_xor(s[e], off, 64);
  }
  if (lane == 0) {
    float m = s[0];
#pragma unroll
    for (int e = 1; e < NE; ++e) m = fmaxf(m, s[e]);
    float p[NE];
#pragma unroll
    for (int e = 0; e < NE; ++e) p[e] = __expf(s[e] - m);
    int i0 = 0;
#pragma unroll
    for (int e = 1; e < NE; ++e) if (s[e] > s[i0]) i0 = e;
    int i1 = (i0 == 0) ? 1 : 0;
#pragma unroll
    for (int e = 0; e < NE; ++e) if (e != i1 && e != i0 && s[e] > s[i1]) i1 = e;
    float p0 = p[i0], p1 = p[i1], inv = 1.f / (p0 + p1);
    idx[2 * t] = i0; idx[2 * t + 1] = i1;
    wts[2 * t] = p0 * inv; wts[2 * t + 1] = p1 * inv;
    atomicAdd(&counts[i0], 1);
    atomicAdd(&counts[i1], 1);
  }
}

// ---------------- fused scan + scatter (single block) ----------------
__global__ __launch_bounds__(1024) void scan_scatter_kernel(
    const int* __restrict__ counts, const int* __restrict__ idx,
    const float* __restrict__ wts, int* __restrict__ offs,
    int* __restrict__ perm, float* __restrict__ wt_slot, int* __restrict__ slot_of) {
  __shared__ int scur[NE];
  __shared__ int soff[NE + 1];
  if (threadIdx.x == 0) {
    int a = 0;
    for (int e = 0; e < NE; ++e) { soff[e] = a; scur[e] = a; a += counts[e]; }
    soff[NE] = a;
  }
  __syncthreads();
  if (threadIdx.x < NE + 1) offs[threadIdx.x] = soff[threadIdx.x];
  for (int t = threadIdx.x; t < T_TOK; t += 1024) {
    for (int k = 0; k < 2; ++k) {
      int e = idx[2 * t + k];
      int pos = atomicAdd(&scur[e], 1);
      perm[pos] = t;
      wt_slot[pos] = wts[2 * t + k];
      slot_of[2 * t + k] = pos;
    }
  }
}

// =====================================================================================
// ffn1: h = silu(X*W1^T) .* (X*W3^T)   BM=256, BN=128, BK=64, 512 thr
// 2 phases/tile (32 MFMA each), staging for t+1 spread 4 loads/phase in consumption
// order: [B1,B1,B3,B3 | A0,A2,A1,A3]. Counted waits: mid-tile vmcnt(4), flip vmcnt(2).
// LDS 128 KiB: A dbuf 2x32KB @0, B1 dbuf 2x16KB @32768(elems), B3 @49152
// Swizzle: chunk (row, j) stored at row-local 16B-slot  pos = j ^ (row&7)
// =====================================================================================
__global__ __launch_bounds__(512, 2) void ffn1_kernel(
    const u16* __restrict__ xb, const u16* __restrict__ w1b, const u16* __restrict__ w3b,
    const int* __restrict__ offs, const int* __restrict__ perm, u16* __restrict__ h) {
  __shared__ u16 smem[65536];
  int tid = threadIdx.x, wave = tid >> 6, lane = tid & 63;
  int wr = wave >> 2, wc = wave & 3;
  int lrow = lane & 15, lq = lane >> 4;
  int e = -1, mblk = 0;
  {
    int acc = 0;
    for (int i = 0; i < NE; ++i) {
      int c = offs[i + 1] - offs[i];
      int nb = (c + 255) >> 8;
      if ((int)blockIdx.y < acc + nb) { e = i; mblk = (int)blockIdx.y - acc; break; }
      acc += nb;
    }
  }
  if (e < 0) return;
  int seg = offs[e], cnt = offs[e + 1] - seg;
  int fBase = blockIdx.x * 128;

  const u16* gA[4];
#pragma unroll
  for (int s = 0; s < 4; ++s) {
    int row = s * 64 + wave * 8 + (lane >> 3);
    int j = (lane & 7) ^ (row & 7);
    int r = mblk * 256 + row; if (r > cnt - 1) r = cnt - 1;
    int tok = perm[seg + r];
    gA[s] = xb + (size_t)tok * DIM + j * 8;
  }
  const u16 *gB1[2], *gB3[2];
  size_t wb = (size_t)e * DFF * DIM;
#pragma unroll
  for (int s = 0; s < 2; ++s) {
    int row = s * 64 + wave * 8 + (lane >> 3);
    int j = (lane & 7) ^ (row & 7);
    size_t fb = wb + (size_t)(fBase + row) * DIM + j * 8;
    gB1[s] = w1b + fb;
    gB3[s] = w3b + fb;
  }
  int p8_0 = ((0 | lq) ^ (lane & 7)) * 8;
  int p8_1 = ((4 | lq) ^ (lane & 7)) * 8;

  f32x4 acc1[8][2], acc3[8][2];
#pragma unroll
  for (int i = 0; i < 8; ++i)
#pragma unroll
    for (int j = 0; j < 2; ++j) {
      acc1[i][j] = (f32x4){0.f, 0.f, 0.f, 0.f};
      acc3[i][j] = (f32x4){0.f, 0.f, 0.f, 0.f};
    }

  // stage halves (issue order == consumption order)
#define ST_B(kb, b)                                                                   \
  do {                                                                                \
    gl_lds16(gB1[0] + (kb), &smem[32768 + (b) * 8192 + 0 * 4096 + wave * 512]);       \
    gl_lds16(gB1[1] + (kb), &smem[32768 + (b) * 8192 + 1 * 4096 + wave * 512]);       \
    gl_lds16(gB3[0] + (kb), &smem[49152 + (b) * 8192 + 0 * 4096 + wave * 512]);       \
    gl_lds16(gB3[1] + (kb), &smem[49152 + (b) * 8192 + 1 * 4096 + wave * 512]);       \
  } while (0)
#define ST_A(kb, b)                                                                   \
  do {                                                                                \
    gl_lds16(gA[0] + (kb), &smem[(b) * 16384 + 0 * 4096 + wave * 512]);               \
    gl_lds16(gA[2] + (kb), &smem[(b) * 16384 + 2 * 4096 + wave * 512]);               \
    gl_lds16(gA[1] + (kb), &smem[(b) * 16384 + 1 * 4096 + wave * 512]);               \
    gl_lds16(gA[3] + (kb), &smem[(b) * 16384 + 3 * 4096 + wave * 512]);               \
  } while (0)

  // prologue: tile 0, leave the 2 youngest (A1,A3) in flight
  ST_B(0, 0);
  ST_A(0, 0);
  asm volatile("s_waitcnt vmcnt(2)" ::: "memory");
  __builtin_amdgcn_s_barrier();

  int wrow = wr * 128 + lrow;
  int brow = wc * 32 + lrow;
  const int NT = DIM / 64;  // 16
  for (int t = 0; t < NT; ++t) {
    int buf = t & 1, nbf = buf ^ 1;
    const u16* lA  = &smem[buf * 16384];
    const u16* lB1 = &smem[32768 + buf * 8192];
    const u16* lB3 = &smem[49152 + buf * 8192];
    bool pf = (t + 1 < NT);
    int kn = (t + 1) * 64;
    bf16x8 b10[2], b11[2], b30[2], b31[2];

    // ---- phase 0: rows wr*128+[0..63], kk=0 and kk=1 (32 MFMA) ----
    {
      bf16x8 a0[4], a1[4];
#pragma unroll
      for (int q = 0; q < 4; ++q) {
        a0[q] = *(const bf16x8*)&lA[(wrow + q * 16) * 64 + p8_0];
        a1[q] = *(const bf16x8*)&lA[(wrow + q * 16) * 64 + p8_1];
      }
#pragma unroll
      for (int ni = 0; ni < 2; ++ni) {
        b10[ni] = *(const bf16x8*)&lB1[(brow + ni * 16) * 64 + p8_0];
        b11[ni] = *(const bf16x8*)&lB1[(brow + ni * 16) * 64 + p8_1];
        b30[ni] = *(const bf16x8*)&lB3[(brow + ni * 16) * 64 + p8_0];
        b31[ni] = *(const bf16x8*)&lB3[(brow + ni * 16) * 64 + p8_1];
      }
      if (pf) ST_B(kn, nbf);
      __builtin_amdgcn_s_barrier();
      asm volatile("s_waitcnt lgkmcnt(0)" ::: "memory");
      __builtin_amdgcn_sched_barrier(0);
      __builtin_amdgcn_s_setprio(1);
#pragma unroll
      for (int q = 0; q < 4; ++q)
#pragma unroll
        for (int ni = 0; ni < 2; ++ni) {
          acc1[q][ni] = __builtin_amdgcn_mfma_f32_16x16x32_bf16(a0[q], b10[ni], acc1[q][ni], 0, 0, 0);
          acc1[q][ni] = __builtin_amdgcn_mfma_f32_16x16x32_bf16(a1[q], b11[ni], acc1[q][ni], 0, 0, 0);
          acc3[q][ni] = __builtin_amdgcn_mfma_f32_16x16x32_bf16(a0[q], b30[ni], acc3[q][ni], 0, 0, 0);
          acc3[q][ni] = __builtin_amdgcn_mfma_f32_16x16x32_bf16(a1[q], b31[ni], acc3[q][ni], 0, 0, 0);
        }
      __builtin_amdgcn_s_setprio(0);
      // mid-tile: ensure this tile's A1,A3 landed (leave t+1's B loads in flight)
      if (pf) asm volatile("s_waitcnt vmcnt(4)" ::: "memory");
      else    asm volatile("s_waitcnt vmcnt(0)" ::: "memory");
      __builtin_amdgcn_s_barrier();
    }
    // ---- phase 1: rows wr*128+64+[0..63], kk=0 and kk=1 (32 MFMA) ----
    {
      bf16x8 a0[4], a1[4];
#pragma unroll
      for (int q = 0; q < 4; ++q) {
        a0[q] = *(const bf16x8*)&lA[(wrow + 64 + q * 16) * 64 + p8_0];
        a1[q] = *(const bf16x8*)&lA[(wrow + 64 + q * 16) * 64 + p8_1];
      }
      if (pf) ST_A(kn, nbf);
      __builtin_amdgcn_s_barrier();
      asm volatile("s_waitcnt lgkmcnt(0)" ::: "memory");
      __builtin_amdgcn_sched_barrier(0);
      __builtin_amdgcn_s_setprio(1);
#pragma unroll
      for (int q = 0; q < 4; ++q)
#pragma unroll
        for (int ni = 0; ni < 2; ++ni) {
          acc1[4 + q][ni] = __builtin_amdgcn_mfma_f32_16x16x32_bf16(a0[q], b10[ni], acc1[4 + q][ni], 0, 0, 0);
          acc1[4 + q][ni] = __builtin_amdgcn_mfma_f32_16x16x32_bf16(a1[q], b11[ni], acc1[4 + q][ni], 0, 0, 0);
          acc3[4 + q][ni] = __builtin_amdgcn_mfma_f32_16x16x32_bf16(a0[q], b30[ni], acc3[4 + q][ni], 0, 0, 0);
          acc3[4 + q][ni] = __builtin_amdgcn_mfma_f32_16x16x32_bf16(a1[q], b31[ni], acc3[4 + q][ni], 0, 0, 0);
        }
      __builtin_amdgcn_s_setprio(0);
      // flip: ensure t+1's first-6 (B1,B3,A0,A2) landed; A1,A3 may stay in flight
      if (pf) asm volatile("s_waitcnt vmcnt(2)" ::: "memory");
      __builtin_amdgcn_s_barrier();
    }
  }
#undef ST_A
#undef ST_B
  // epilogue: silu(c1)*c3 -> h
#pragma unroll
  for (int mi = 0; mi < 8; ++mi) {
#pragma unroll
    for (int jj = 0; jj < 4; ++jj) {
      int lr = mblk * 256 + wr * 128 + mi * 16 + lq * 4 + jj;
      if (lr < cnt) {
        size_t slot = (size_t)(seg + lr);
#pragma unroll
        for (int ni = 0; ni < 2; ++ni) {
          float c1v = acc1[mi][ni][jj], c3v = acc3[mi][ni][jj];
          float sv = c1v / (1.f + __expf(-c1v));
          int f = fBase + wc * 32 + ni * 16 + lrow;
          h[slot * DFF + f] = f2bf(sv * c3v);
        }
      }
    }
  }
}

// =====================================================================================
// ffn2: y = wt * (H * W2^T)   BM=128, BN=128, BK=64, 512 thr, 1 phase/tile (16 MFMA)
// TRIPLE buffer (96 KiB): stage t+2 during tile t -> full-tile cover, flip vmcnt(4).
// LDS elems: A buf b @ b*8192, B buf b @ 24576 + b*8192
// =====================================================================================
__global__ __launch_bounds__(512, 2) void ffn2_kernel(
    const u16* __restrict__ h, const u16* __restrict__ w2b,
    const int* __restrict__ offs, const float* __restrict__ wt_slot,
    float* __restrict__ y) {
  __shared__ u16 smem[49152];
  int tid = threadIdx.x, wave = tid >> 6, lane = tid & 63;
  int wr = wave >> 2, wc = wave & 3;
  int lrow = lane & 15, lq = lane >> 4;
  int e = -1, mblk = 0;
  {
    int acc = 0;
    for (int i = 0; i < NE; ++i) {
      int c = offs[i + 1] - offs[i];
      int nb = (c + 127) >> 7;
      if ((int)blockIdx.y < acc + nb) { e = i; mblk = (int)blockIdx.y - acc; break; }
      acc += nb;
    }
  }
  if (e < 0) return;
  int seg = offs[e], cnt = offs[e + 1] - seg;
  int dBase = blockIdx.x * 128;

  const u16 *gA[2], *gB[2];
  size_t wb = (size_t)e * DIM * DFF;
#pragma unroll
  for (int s = 0; s < 2; ++s) {
    int row = s * 64 + wave * 8 + (lane >> 3);
    int j = (lane & 7) ^ (row & 7);
    int r = mblk * 128 + row; if (r > cnt - 1) r = cnt - 1;
    gA[s] = h + (size_t)(seg + r) * DFF + j * 8;
    gB[s] = w2b + wb + (size_t)(dBase + row) * DFF + j * 8;
  }
  int p8_0 = ((0 | lq) ^ (lane & 7)) * 8;
  int p8_1 = ((4 | lq) ^ (lane & 7)) * 8;

  f32x4 acc[4][2];
#pragma unroll
  for (int i = 0; i < 4; ++i)
#pragma unroll
    for (int j = 0; j < 2; ++j) acc[i][j] = (f32x4){0.f, 0.f, 0.f, 0.f};

#define STAGE2(kt, b)                                                                 \
  do {                                                                                \
    int kb = (kt) * 64;                                                               \
    gl_lds16(gA[0] + kb, &smem[(b) * 8192 + 0 * 4096 + wave * 512]);                  \
    gl_lds16(gA[1] + kb, &smem[(b) * 8192 + 1 * 4096 + wave * 512]);                  \
    gl_lds16(gB[0] + kb, &smem[24576 + (b) * 8192 + 0 * 4096 + wave * 512]);          \
    gl_lds16(gB[1] + kb, &smem[24576 + (b) * 8192 + 1 * 4096 + wave * 512]);          \
  } while (0)

  STAGE2(0, 0);
  STAGE2(1, 1);
  asm volatile("s_waitcnt vmcnt(4)" ::: "memory");
  __builtin_amdgcn_s_barrier();

  int wrow = wr * 64 + lrow;
  int brow = wc * 32 + lrow;
  const int NT = DFF / 64;  // 32
  for (int t = 0; t < NT; ++t) {
    int buf = t % 3;
    const u16* lA = &smem[buf * 8192];
    const u16* lB = &smem[24576 + buf * 8192];
    bool pf = (t + 2 < NT);
    bf16x8 a0[4], a1[4], b0[2], b1[2];
#pragma unroll
    for (int q = 0; q < 4; ++q) {
      a0[q] = *(const bf16x8*)&lA[(wrow + q * 16) * 64 + p8_0];
      a1[q] = *(const bf16x8*)&lA[(wrow + q * 16) * 64 + p8_1];
    }
#pragma unroll
    for (int ni = 0; ni < 2; ++ni) {
      b0[ni] = *(const bf16x8*)&lB[(brow + ni * 16) * 64 + p8_0];
      b1[ni] = *(const bf16x8*)&lB[(brow + ni * 16) * 64 + p8_1];
    }
    if (pf) STAGE2(t + 2, (t + 2) % 3);
    __builtin_amdgcn_s_barrier();
    asm volatile("s_waitcnt lgkmcnt(0)" ::: "memory");
    __builtin_amdgcn_sched_barrier(0);
    __builtin_amdgcn_s_setprio(1);
#pragma unroll
    for (int q = 0; q < 4; ++q)
#pragma unroll
      for (int ni = 0; ni < 2; ++ni) {
        acc[q][ni] = __builtin_amdgcn_mfma_f32_16x16x32_bf16(a0[q], b0[ni], acc[q][ni], 0, 0, 0);
        acc[q][ni] = __builtin_amdgcn_mfma_f32_16x16x32_bf16(a1[q], b1[ni], acc[q][ni], 0, 0, 0);
      }
    __builtin_amdgcn_s_setprio(0);
    // flip: ensure t+1's 4 loads landed; t+2's 4 stay in flight
    if (pf) asm volatile("s_waitcnt vmcnt(4)" ::: "memory");
    else    asm volatile("s_waitcnt vmcnt(0)" ::: "memory");
    __builtin_amdgcn_s_barrier();
  }
#undef STAGE2
#pragma unroll
  for (int mi = 0; mi < 4; ++mi) {
#pragma unroll
    for (int jj = 0; jj < 4; ++jj) {
      int lr = mblk * 128 + wr * 64 + mi * 16 + lq * 4 + jj;
      if (lr < cnt) {
        size_t slot = (size_t)(seg + lr);
        float wt = wt_slot[slot];
#pragma unroll
        for (int ni = 0; ni < 2; ++ni) {
          int d = dBase + wc * 32 + ni * 16 + lrow;
          y[slot * DIM + d] = wt * acc[mi][ni][jj];
        }
      }
    }
  }
}

// ---------------- combine: out[t] = y[slot0] + y[slot1] ----------------
__global__ __launch_bounds__(256) void combine_kernel(const float* __restrict__ y,
                                                      const int* __restrict__ slot_of,
                                                      float* __restrict__ out) {
  int t = blockIdx.x, dv = threadIdx.x;
  int s0 = slot_of[2 * t], s1 = slot_of[2 * t + 1];
  const float4* y4 = (const float4*)y;
  float4 a = y4[(size_t)s0 * 256 + dv];
  float4 b = y4[(size_t)s1 * 256 + dv];
  float4 r; r.x = a.x + b.x; r.y = a.y + b.y; r.z = a.z + b.z; r.w = a.w + b.w;
  ((float4*)out)[(size_t)t * 256 + dv] = r;
}

extern "C" void kernel_launch(void* const* d_in, const int* in_sizes, int n_in,
                              void* d_out, int out_size, void* d_ws, size_t ws_size,
                              hipStream_t stream) {
  const float* x  = (const float*)d_in[0];
  const float* gw = (const float*)d_in[1];
  const float* w1 = (const float*)d_in[2];
  const float* w2 = (const float*)d_in[3];
  const float* w3 = (const float*)d_in[4];
  float* out = (float*)d_out;

  char* ws = (char*)d_ws;
  size_t o = 0;
  u16* xb  = (u16*)(ws + o); o += (size_t)T_TOK * DIM * 2;
  u16* w1b = (u16*)(ws + o); o += (size_t)NE * DFF * DIM * 2;
  u16* w3b = (u16*)(ws + o); o += (size_t)NE * DFF * DIM * 2;
  u16* w2b = (u16*)(ws + o); o += (size_t)NE * DIM * DFF * 2;
  u16* h   = (u16*)(ws + o); o += (size_t)NSLOT * DFF * 2;
  float* y = (float*)(ws + o); o += (size_t)NSLOT * DIM * 4;
  int* idx      = (int*)(ws + o); o += NSLOT * 4;
  float* wts    = (float*)(ws + o); o += NSLOT * 4;
  int* slot_of  = (int*)(ws + o); o += NSLOT * 4;
  int* perm     = (int*)(ws + o); o += NSLOT * 4;
  float* wt_slot= (float*)(ws + o); o += NSLOT * 4;
  int* counts   = (int*)(ws + o); o += 16 * 4;
  int* offs     = (int*)(ws + o); o += 16 * 4;
  if (o > ws_size) return;

  cvtw_kernel<<<2048, 256, 0, stream>>>(w1, w2, w3, w1b, w2b, w3b, counts);
  gate_kernel<<<T_TOK / 4, 256, 0, stream>>>(x, gw, xb, idx, wts, counts);
  scan_scatter_kernel<<<1, 1024, 0, stream>>>(counts, idx, wts, offs, perm, wt_slot, slot_of);
  ffn1_kernel<<<dim3(16, 40), 512, 0, stream>>>(xb, w1b, w3b, offs, perm, h);
  ffn2_kernel<<<dim3(8, 71), 512, 0, stream>>>(h, w2b, offs, wt_slot, y);
  combine_kernel<<<T_TOK, 256, 0, stream>>>(y, slot_of, out);
}

// Round 5
// 326.735 us; speedup vs baseline: 1.1592x; 1.0356x over previous
//
#include <hip/hip_runtime.h>
#include <hip/hip_bf16.h>
#include <cstdint>
#include <cstddef>

#define T_TOK 4096
#define DIM   1024
#define NE    8
#define DFF   2048
#define NSLOT 8192   // T_TOK * TOP_K

typedef __bf16 bf16x8 __attribute__((ext_vector_type(8)));
typedef float  f32x4  __attribute__((ext_vector_type(4)));
typedef unsigned short u16;
typedef unsigned short u16x8 __attribute__((ext_vector_type(8)));

__device__ __forceinline__ u16 f2bf(float f) {
  union { float f; uint32_t u; } v; v.f = f;
  uint32_t r = (v.u + 0x7FFFu + ((v.u >> 16) & 1u)) >> 16;
  return (u16)r;
}

typedef const __attribute__((address_space(1))) uint32_t* gas_ptr;
typedef __attribute__((address_space(3))) uint32_t* las_ptr;
__device__ __forceinline__ void gl_lds16(const void* g, void* l) {
  __builtin_amdgcn_global_load_lds((gas_ptr)g, (las_ptr)l, 16, 0, 0);
}

#define VM8 asm volatile("s_waitcnt vmcnt(8)" ::: "memory")
#define VM4 asm volatile("s_waitcnt vmcnt(4)" ::: "memory")
#define VM0 asm volatile("s_waitcnt vmcnt(0)" ::: "memory")
#define VMN ((void)0)

// ---------------- weight conversion fp32 -> bf16 (w1,w2,w3) + counts init ----------------
__global__ __launch_bounds__(256) void cvtw_kernel(const float* __restrict__ w1,
                                                   const float* __restrict__ w2,
                                                   const float* __restrict__ w3,
                                                   u16* __restrict__ w1b,
                                                   u16* __restrict__ w2b,
                                                   u16* __restrict__ w3b,
                                                   int* __restrict__ counts) {
  if (blockIdx.x == 0 && threadIdx.x < NE) counts[threadIdx.x] = 0;
  const long n = (long)NE * DFF * DIM;
  long stride = (long)gridDim.x * 256 * 8;
  for (long i = ((long)blockIdx.x * 256 + threadIdx.x) * 8; i < 3 * n; i += stride) {
    const float* s; u16* d; long off;
    if (i < n)          { s = w1; d = w1b; off = i; }
    else if (i < 2 * n) { s = w2; d = w2b; off = i - n; }
    else                { s = w3; d = w3b; off = i - 2 * n; }
    float4 a = *(const float4*)(s + off);
    float4 b = *(const float4*)(s + off + 4);
    u16x8 r;
    r[0] = f2bf(a.x); r[1] = f2bf(a.y); r[2] = f2bf(a.z); r[3] = f2bf(a.w);
    r[4] = f2bf(b.x); r[5] = f2bf(b.y); r[6] = f2bf(b.z); r[7] = f2bf(b.w);
    *(u16x8*)(d + off) = r;
  }
}

// ---------------- gate: scores fp32, softmax, top-2; also emits xb (bf16 x) ----------------
__global__ __launch_bounds__(256) void gate_kernel(const float* __restrict__ x,
                                                   const float* __restrict__ gw,
                                                   u16* __restrict__ xb,
                                                   int* __restrict__ idx,
                                                   float* __restrict__ wts,
                                                   int* __restrict__ counts) {
  __shared__ float sgw[NE * DIM];
  int tid = threadIdx.x;
  for (int i = tid; i < NE * DIM; i += 256) sgw[i] = gw[i];
  __syncthreads();
  int wave = tid >> 6, lane = tid & 63;
  int t = blockIdx.x * 4 + wave;
  float xv[16];
#pragma unroll
  for (int j = 0; j < 16; ++j) xv[j] = x[(size_t)t * DIM + lane + j * 64];
#pragma unroll
  for (int j = 0; j < 16; ++j) xb[(size_t)t * DIM + lane + j * 64] = f2bf(xv[j]);
  float s[NE];
#pragma unroll
  for (int e = 0; e < NE; ++e) {
    float a = 0.f;
#pragma unroll
    for (int j = 0; j < 16; ++j) a += xv[j] * sgw[e * DIM + lane + j * 64];
    s[e] = a;
  }
#pragma unroll
  for (int off = 32; off > 0; off >>= 1) {
#pragma unroll
    for (int e = 0; e < NE; ++e) s[e] += __shfl_xor(s[e], off, 64);
  }
  if (lane == 0) {
    float m = s[0];
#pragma unroll
    for (int e = 1; e < NE; ++e) m = fmaxf(m, s[e]);
    float p[NE];
#pragma unroll
    for (int e = 0; e < NE; ++e) p[e] = __expf(s[e] - m);
    int i0 = 0;
#pragma unroll
    for (int e = 1; e < NE; ++e) if (s[e] > s[i0]) i0 = e;
    int i1 = (i0 == 0) ? 1 : 0;
#pragma unroll
    for (int e = 0; e < NE; ++e) if (e != i1 && e != i0 && s[e] > s[i1]) i1 = e;
    float p0 = p[i0], p1 = p[i1], inv = 1.f / (p0 + p1);
    idx[2 * t] = i0; idx[2 * t + 1] = i1;
    wts[2 * t] = p0 * inv; wts[2 * t + 1] = p1 * inv;
    atomicAdd(&counts[i0], 1);
    atomicAdd(&counts[i1], 1);
  }
}

// ---------------- fused scan + scatter (single block) ----------------
__global__ __launch_bounds__(1024) void scan_scatter_kernel(
    const int* __restrict__ counts, const int* __restrict__ idx,
    const float* __restrict__ wts, int* __restrict__ offs,
    int* __restrict__ perm, float* __restrict__ wt_slot, int* __restrict__ slot_of) {
  __shared__ int scur[NE];
  __shared__ int soff[NE + 1];
  if (threadIdx.x == 0) {
    int a = 0;
    for (int e = 0; e < NE; ++e) { soff[e] = a; scur[e] = a; a += counts[e]; }
    soff[NE] = a;
  }
  __syncthreads();
  if (threadIdx.x < NE + 1) offs[threadIdx.x] = soff[threadIdx.x];
  for (int t = threadIdx.x; t < T_TOK; t += 1024) {
    for (int k = 0; k < 2; ++k) {
      int e = idx[2 * t + k];
      int pos = atomicAdd(&scur[e], 1);
      perm[pos] = t;
      wt_slot[pos] = wts[2 * t + k];
      slot_of[2 * t + k] = pos;
    }
  }
}

// =====================================================================================
// ffn1: h = silu(X*W1^T) .* (X*W3^T)   BM=256, BN=128, BK=32, 512 thr, 8 waves (2x4)
// 4-deep circular LDS (128 KiB), 1 barrier/tile, vmcnt(8) steady state (~2.5-tile cover)
// Swizzle: 16B-chunk pos p holds global chunk p ^ ((row>>1)&3)  -> 2-way banks (free)
// LDS elems: A buf b @ b*8192 (16KB), B1 @ 32768 + b*4096, B3 @ 49152 + b*4096
// =====================================================================================
__global__ __launch_bounds__(512, 2) void ffn1_kernel(
    const u16* __restrict__ xb, const u16* __restrict__ w1b, const u16* __restrict__ w3b,
    const int* __restrict__ offs, const int* __restrict__ perm, u16* __restrict__ h) {
  __shared__ u16 smem[65536];
  int tid = threadIdx.x, wave = tid >> 6, lane = tid & 63;
  int wr = wave >> 2, wc = wave & 3;
  int lrow = lane & 15, lq = lane >> 4;
  // XCD-aware bijective swizzle of flattened grid (640 = 8 * 80)
  int bid = blockIdx.x;
  int nid = (bid & 7) * 80 + (bid >> 3);
  int bx = nid & 15;   // f-tile, 16 of them share one token-tile -> same XCD
  int by = nid >> 4;   // 0..39
  int e = -1, mblk = 0;
  {
    int acc = 0;
    for (int i = 0; i < NE; ++i) {
      int c = offs[i + 1] - offs[i];
      int nb = (c + 255) >> 8;
      if (by < acc + nb) { e = i; mblk = by - acc; break; }
      acc += nb;
    }
  }
  if (e < 0) return;
  int seg = offs[e], cnt = offs[e + 1] - seg;
  int fBase = bx * 128;

  // staging source pointers (pre-swizzled per-lane global chunk)
  const u16* gA[2];
#pragma unroll
  for (int s = 0; s < 2; ++s) {
    int row = wave * 32 + s * 16 + (lane >> 2);         // LDS row 0..255
    int ch = (lane & 3) ^ ((row >> 1) & 3);
    int r = mblk * 256 + row; if (r > cnt - 1) r = cnt - 1;
    int tok = perm[seg + r];
    gA[s] = xb + (size_t)tok * DIM + ch * 8;
  }
  size_t wb = (size_t)e * DFF * DIM;
  int rowB = wave * 16 + (lane >> 2);                    // LDS row 0..127
  int chB = (lane & 3) ^ ((rowB >> 1) & 3);
  const u16* gB1 = w1b + wb + (size_t)(fBase + rowB) * DIM + chB * 8;
  const u16* gB3 = w3b + wb + (size_t)(fBase + rowB) * DIM + chB * 8;

  // fragment-read offsets (elems), p8 uniform across m/n since strides are mult of 8 rows
  int p8 = (lq ^ ((lrow >> 1) & 3)) * 8;
  int aoff[8], boff[2];
#pragma unroll
  for (int m = 0; m < 8; ++m) aoff[m] = (wr * 128 + m * 16 + lrow) * 32 + p8;
#pragma unroll
  for (int n = 0; n < 2; ++n) boff[n] = (wc * 32 + n * 16 + lrow) * 32 + p8;

  f32x4 acc1[8][2], acc3[8][2];
#pragma unroll
  for (int i = 0; i < 8; ++i)
#pragma unroll
    for (int j = 0; j < 2; ++j) {
      acc1[i][j] = (f32x4){0.f, 0.f, 0.f, 0.f};
      acc3[i][j] = (f32x4){0.f, 0.f, 0.f, 0.f};
    }

#define STAGE_F1(kt)                                                         \
  do {                                                                       \
    int kb = (kt) * 32, b = (kt) & 3;                                        \
    gl_lds16(gA[0] + kb, &smem[b * 8192 + wave * 1024]);                     \
    gl_lds16(gA[1] + kb, &smem[b * 8192 + wave * 1024 + 512]);               \
    gl_lds16(gB1 + kb, &smem[32768 + b * 4096 + wave * 512]);                \
    gl_lds16(gB3 + kb, &smem[49152 + b * 4096 + wave * 512]);                \
  } while (0)

#define F1_TILE(T, STG, VM, BAR)                                             \
  do {                                                                       \
    int buf = (T) & 3;                                                       \
    const u16* lA = &smem[buf * 8192];                                       \
    const u16* lB1 = &smem[32768 + buf * 4096];                              \
    const u16* lB3 = &smem[49152 + buf * 4096];                              \
    bf16x8 a[8], b1[2], b3[2];                                               \
    _Pragma("unroll") for (int m = 0; m < 8; ++m)                            \
        a[m] = *(const bf16x8*)&lA[aoff[m]];                                 \
    _Pragma("unroll") for (int n = 0; n < 2; ++n) {                          \
      b1[n] = *(const bf16x8*)&lB1[boff[n]];                                 \
      b3[n] = *(const bf16x8*)&lB3[boff[n]];                                 \
    }                                                                        \
    if (STG) STAGE_F1((T) + 3);                                              \
    asm volatile("s_waitcnt lgkmcnt(0)" ::: "memory");                       \
    __builtin_amdgcn_sched_barrier(0);                                       \
    __builtin_amdgcn_s_setprio(1);                                           \
    _Pragma("unroll") for (int m = 0; m < 8; ++m)                            \
        _Pragma("unroll") for (int n = 0; n < 2; ++n) {                      \
      acc1[m][n] = __builtin_amdgcn_mfma_f32_16x16x32_bf16(a[m], b1[n], acc1[m][n], 0, 0, 0); \
      acc3[m][n] = __builtin_amdgcn_mfma_f32_16x16x32_bf16(a[m], b3[n], acc3[m][n], 0, 0, 0); \
    }                                                                        \
    __builtin_amdgcn_s_setprio(0);                                           \
    VM;                                                                      \
    if (BAR) __builtin_amdgcn_s_barrier();                                   \
  } while (0)

  // prologue: 3 tiles in flight
  STAGE_F1(0); STAGE_F1(1); STAGE_F1(2);
  VM8;  // tile 0 landed (leave 1,2 in flight)
  __builtin_amdgcn_s_barrier();

  const int NT = DIM / 32;  // 32
  for (int t = 0; t < NT - 3; ++t) F1_TILE(t, true, VM8, true);
  F1_TILE(NT - 3, false, VM4, true);
  F1_TILE(NT - 2, false, VM0, true);
  F1_TILE(NT - 1, false, VMN, false);
#undef F1_TILE
#undef STAGE_F1

  // epilogue: silu(c1)*c3 -> h
#pragma unroll
  for (int mi = 0; mi < 8; ++mi) {
#pragma unroll
    for (int jj = 0; jj < 4; ++jj) {
      int lr = mblk * 256 + wr * 128 + mi * 16 + lq * 4 + jj;
      if (lr < cnt) {
        size_t slot = (size_t)(seg + lr);
#pragma unroll
        for (int ni = 0; ni < 2; ++ni) {
          float c1v = acc1[mi][ni][jj], c3v = acc3[mi][ni][jj];
          float sv = c1v / (1.f + __expf(-c1v));
          int f = fBase + wc * 32 + ni * 16 + lrow;
          h[slot * DFF + f] = f2bf(sv * c3v);
        }
      }
    }
  }
}

// =====================================================================================
// ffn2: y = wt * (H * W2^T)   BM=128, BN=128, BK=32, 256 thr, 4 waves (2x2)
// 4-deep circular LDS (64 KiB -> 2 blocks/CU), 1 barrier/tile, vmcnt(8) steady
// LDS elems: A buf b @ b*4096, B @ 16384 + b*4096
// =====================================================================================
__global__ __launch_bounds__(256, 2) void ffn2_kernel(
    const u16* __restrict__ h, const u16* __restrict__ w2b,
    const int* __restrict__ offs, const float* __restrict__ wt_slot,
    float* __restrict__ y) {
  __shared__ u16 smem[32768];
  int tid = threadIdx.x, wave = tid >> 6, lane = tid & 63;
  int wr = wave >> 1, wc = wave & 1;
  int lrow = lane & 15, lq = lane >> 4;
  int bid = blockIdx.x;                 // 568 = 8 * 71
  int nid = (bid & 7) * 71 + (bid >> 3);
  int bx = nid & 7;                     // d-tile (8 share one h-tile)
  int by = nid >> 3;                    // 0..70
  int e = -1, mblk = 0;
  {
    int acc = 0;
    for (int i = 0; i < NE; ++i) {
      int c = offs[i + 1] - offs[i];
      int nb = (c + 127) >> 7;
      if (by < acc + nb) { e = i; mblk = by - acc; break; }
      acc += nb;
    }
  }
  if (e < 0) return;
  int seg = offs[e], cnt = offs[e + 1] - seg;
  int dBase = bx * 128;

  const u16 *gA[2], *gB[2];
  size_t wb = (size_t)e * DIM * DFF;
#pragma unroll
  for (int s = 0; s < 2; ++s) {
    int row = wave * 32 + s * 16 + (lane >> 2);   // LDS row 0..127
    int ch = (lane & 3) ^ ((row >> 1) & 3);
    int r = mblk * 128 + row; if (r > cnt - 1) r = cnt - 1;
    gA[s] = h + (size_t)(seg + r) * DFF + ch * 8;
    gB[s] = w2b + wb + (size_t)(dBase + row) * DFF + ch * 8;
  }

  int p8 = (lq ^ ((lrow >> 1) & 3)) * 8;
  int aoff[4], boff[4];
#pragma unroll
  for (int m = 0; m < 4; ++m) aoff[m] = (wr * 64 + m * 16 + lrow) * 32 + p8;
#pragma unroll
  for (int n = 0; n < 4; ++n) boff[n] = (wc * 64 + n * 16 + lrow) * 32 + p8;

  f32x4 acc[4][4];
#pragma unroll
  for (int i = 0; i < 4; ++i)
#pragma unroll
    for (int j = 0; j < 4; ++j) acc[i][j] = (f32x4){0.f, 0.f, 0.f, 0.f};

#define STAGE_F2(kt)                                                         \
  do {                                                                       \
    int kb = (kt) * 32, b = (kt) & 3;                                        \
    gl_lds16(gA[0] + kb, &smem[b * 4096 + wave * 1024]);                     \
    gl_lds16(gA[1] + kb, &smem[b * 4096 + wave * 1024 + 512]);               \
    gl_lds16(gB[0] + kb, &smem[16384 + b * 4096 + wave * 1024]);             \
    gl_lds16(gB[1] + kb, &smem[16384 + b * 4096 + wave * 1024 + 512]);       \
  } while (0)

#define F2_TILE(T, STG, VM, BAR)                                             \
  do {                                                                       \
    int buf = (T) & 3;                                                       \
    const u16* lA = &smem[buf * 4096];                                       \
    const u16* lB = &smem[16384 + buf * 4096];                               \
    bf16x8 a[4], b[4];                                                       \
    _Pragma("unroll") for (int m = 0; m < 4; ++m)                            \
        a[m] = *(const bf16x8*)&lA[aoff[m]];                                 \
    _Pragma("unroll") for (int n = 0; n < 4; ++n)                            \
        b[n] = *(const bf16x8*)&lB[boff[n]];                                 \
    if (STG) STAGE_F2((T) + 3);                                              \
    asm volatile("s_waitcnt lgkmcnt(0)" ::: "memory");                       \
    __builtin_amdgcn_sched_barrier(0);                                       \
    __builtin_amdgcn_s_setprio(1);                                           \
    _Pragma("unroll") for (int m = 0; m < 4; ++m)                            \
        _Pragma("unroll") for (int n = 0; n < 4; ++n)                        \
            acc[m][n] = __builtin_amdgcn_mfma_f32_16x16x32_bf16(a[m], b[n], acc[m][n], 0, 0, 0); \
    __builtin_amdgcn_s_setprio(0);                                           \
    VM;                                                                      \
    if (BAR) __builtin_amdgcn_s_barrier();                                   \
  } while (0)

  STAGE_F2(0); STAGE_F2(1); STAGE_F2(2);
  VM8;
  __builtin_amdgcn_s_barrier();

  const int NT = DFF / 32;  // 64
  for (int t = 0; t < NT - 3; ++t) F2_TILE(t, true, VM8, true);
  F2_TILE(NT - 3, false, VM4, true);
  F2_TILE(NT - 2, false, VM0, true);
  F2_TILE(NT - 1, false, VMN, false);
#undef F2_TILE
#undef STAGE_F2

#pragma unroll
  for (int mi = 0; mi < 4; ++mi) {
#pragma unroll
    for (int jj = 0; jj < 4; ++jj) {
      int lr = mblk * 128 + wr * 64 + mi * 16 + lq * 4 + jj;
      if (lr < cnt) {
        size_t slot = (size_t)(seg + lr);
        float wt = wt_slot[slot];
#pragma unroll
        for (int ni = 0; ni < 4; ++ni) {
          int d = dBase + wc * 64 + ni * 16 + lrow;
          y[slot * DIM + d] = wt * acc[mi][ni][jj];
        }
      }
    }
  }
}

// ---------------- combine: out[t] = y[slot0] + y[slot1] ----------------
__global__ __launch_bounds__(256) void combine_kernel(const float* __restrict__ y,
                                                      const int* __restrict__ slot_of,
                                                      float* __restrict__ out) {
  int t = blockIdx.x, dv = threadIdx.x;
  int s0 = slot_of[2 * t], s1 = slot_of[2 * t + 1];
  const float4* y4 = (const float4*)y;
  float4 a = y4[(size_t)s0 * 256 + dv];
  float4 b = y4[(size_t)s1 * 256 + dv];
  float4 r; r.x = a.x + b.x; r.y = a.y + b.y; r.z = a.z + b.z; r.w = a.w + b.w;
  ((float4*)out)[(size_t)t * 256 + dv] = r;
}

extern "C" void kernel_launch(void* const* d_in, const int* in_sizes, int n_in,
                              void* d_out, int out_size, void* d_ws, size_t ws_size,
                              hipStream_t stream) {
  const float* x  = (const float*)d_in[0];
  const float* gw = (const float*)d_in[1];
  const float* w1 = (const float*)d_in[2];
  const float* w2 = (const float*)d_in[3];
  const float* w3 = (const float*)d_in[4];
  float* out = (float*)d_out;

  char* ws = (char*)d_ws;
  size_t o = 0;
  u16* xb  = (u16*)(ws + o); o += (size_t)T_TOK * DIM * 2;
  u16* w1b = (u16*)(ws + o); o += (size_t)NE * DFF * DIM * 2;
  u16* w3b = (u16*)(ws + o); o += (size_t)NE * DFF * DIM * 2;
  u16* w2b = (u16*)(ws + o); o += (size_t)NE * DIM * DFF * 2;
  u16* h   = (u16*)(ws + o); o += (size_t)NSLOT * DFF * 2;
  float* y = (float*)(ws + o); o += (size_t)NSLOT * DIM * 4;
  int* idx      = (int*)(ws + o); o += NSLOT * 4;
  float* wts    = (float*)(ws + o); o += NSLOT * 4;
  int* slot_of  = (int*)(ws + o); o += NSLOT * 4;
  int* perm     = (int*)(ws + o); o += NSLOT * 4;
  float* wt_slot= (float*)(ws + o); o += NSLOT * 4;
  int* counts   = (int*)(ws + o); o += 16 * 4;
  int* offs     = (int*)(ws + o); o += 16 * 4;
  if (o > ws_size) return;

  cvtw_kernel<<<2048, 256, 0, stream>>>(w1, w2, w3, w1b, w2b, w3b, counts);
  gate_kernel<<<T_TOK / 4, 256, 0, stream>>>(x, gw, xb, idx, wts, counts);
  scan_scatter_kernel<<<1, 1024, 0, stream>>>(counts, idx, wts, offs, perm, wt_slot, slot_of);
  ffn1_kernel<<<640, 512, 0, stream>>>(xb, w1b, w3b, offs, perm, h);
  ffn2_kernel<<<568, 256, 0, stream>>>(h, w2b, offs, wt_slot, y);
  combine_kernel<<<T_TOK, 256, 0, stream>>>(y, slot_of, out);
}

// Round 6
// 324.418 us; speedup vs baseline: 1.1675x; 1.0071x over previous
//
#include <hip/hip_runtime.h>
#include <hip/hip_bf16.h>
#include <cstdint>
#include <cstddef>

#define T_TOK 4096
#define DIM   1024
#define NE    8
#define DFF   2048
#define NSLOT 8192   // T_TOK * TOP_K

typedef __bf16 bf16x8 __attribute__((ext_vector_type(8)));
typedef float  f32x4  __attribute__((ext_vector_type(4)));
typedef unsigned short u16;
typedef unsigned short u16x8 __attribute__((ext_vector_type(8)));

__device__ __forceinline__ u16 f2bf(float f) {
  union { float f; uint32_t u; } v; v.f = f;
  uint32_t r = (v.u + 0x7FFFu + ((v.u >> 16) & 1u)) >> 16;
  return (u16)r;
}

typedef const __attribute__((address_space(1))) uint32_t* gas_ptr;
typedef __attribute__((address_space(3))) uint32_t* las_ptr;
__device__ __forceinline__ void gl_lds16(const void* g, void* l) {
  __builtin_amdgcn_global_load_lds((gas_ptr)g, (las_ptr)l, 16, 0, 0);
}

#define VM3 asm volatile("s_waitcnt vmcnt(3)" ::: "memory")
#define VM2 asm volatile("s_waitcnt vmcnt(2)" ::: "memory")
#define VM0 asm volatile("s_waitcnt vmcnt(0)" ::: "memory")
#define VMN ((void)0)

// ---------------- weight conversion fp32 -> bf16 (w1,w2,w3) + counts init ----------------
__global__ __launch_bounds__(256) void cvtw_kernel(const float* __restrict__ w1,
                                                   const float* __restrict__ w2,
                                                   const float* __restrict__ w3,
                                                   u16* __restrict__ w1b,
                                                   u16* __restrict__ w2b,
                                                   u16* __restrict__ w3b,
                                                   int* __restrict__ counts) {
  if (blockIdx.x == 0 && threadIdx.x < NE) counts[threadIdx.x] = 0;
  const long n = (long)NE * DFF * DIM;
  long stride = (long)gridDim.x * 256 * 8;
  for (long i = ((long)blockIdx.x * 256 + threadIdx.x) * 8; i < 3 * n; i += stride) {
    const float* s; u16* d; long off;
    if (i < n)          { s = w1; d = w1b; off = i; }
    else if (i < 2 * n) { s = w2; d = w2b; off = i - n; }
    else                { s = w3; d = w3b; off = i - 2 * n; }
    float4 a = *(const float4*)(s + off);
    float4 b = *(const float4*)(s + off + 4);
    u16x8 r;
    r[0] = f2bf(a.x); r[1] = f2bf(a.y); r[2] = f2bf(a.z); r[3] = f2bf(a.w);
    r[4] = f2bf(b.x); r[5] = f2bf(b.y); r[6] = f2bf(b.z); r[7] = f2bf(b.w);
    *(u16x8*)(d + off) = r;
  }
}

// ---------------- gate: scores fp32, softmax, top-2; also emits xb (bf16 x) ----------------
__global__ __launch_bounds__(256) void gate_kernel(const float* __restrict__ x,
                                                   const float* __restrict__ gw,
                                                   u16* __restrict__ xb,
                                                   int* __restrict__ idx,
                                                   float* __restrict__ wts,
                                                   int* __restrict__ counts) {
  __shared__ float sgw[NE * DIM];
  int tid = threadIdx.x;
  for (int i = tid; i < NE * DIM; i += 256) sgw[i] = gw[i];
  __syncthreads();
  int wave = tid >> 6, lane = tid & 63;
  int t = blockIdx.x * 4 + wave;
  float xv[16];
#pragma unroll
  for (int j = 0; j < 16; ++j) xv[j] = x[(size_t)t * DIM + lane + j * 64];
#pragma unroll
  for (int j = 0; j < 16; ++j) xb[(size_t)t * DIM + lane + j * 64] = f2bf(xv[j]);
  float s[NE];
#pragma unroll
  for (int e = 0; e < NE; ++e) {
    float a = 0.f;
#pragma unroll
    for (int j = 0; j < 16; ++j) a += xv[j] * sgw[e * DIM + lane + j * 64];
    s[e] = a;
  }
#pragma unroll
  for (int off = 32; off > 0; off >>= 1) {
#pragma unroll
    for (int e = 0; e < NE; ++e) s[e] += __shfl_xor(s[e], off, 64);
  }
  if (lane == 0) {
    float m = s[0];
#pragma unroll
    for (int e = 1; e < NE; ++e) m = fmaxf(m, s[e]);
    float p[NE];
#pragma unroll
    for (int e = 0; e < NE; ++e) p[e] = __expf(s[e] - m);
    int i0 = 0;
#pragma unroll
    for (int e = 1; e < NE; ++e) if (s[e] > s[i0]) i0 = e;
    int i1 = (i0 == 0) ? 1 : 0;
#pragma unroll
    for (int e = 0; e < NE; ++e) if (e != i1 && e != i0 && s[e] > s[i1]) i1 = e;
    float p0 = p[i0], p1 = p[i1], inv = 1.f / (p0 + p1);
    idx[2 * t] = i0; idx[2 * t + 1] = i1;
    wts[2 * t] = p0 * inv; wts[2 * t + 1] = p1 * inv;
    atomicAdd(&counts[i0], 1);
    atomicAdd(&counts[i1], 1);
  }
}

// ---------------- fused scan + scatter (single block) ----------------
__global__ __launch_bounds__(1024) void scan_scatter_kernel(
    const int* __restrict__ counts, const int* __restrict__ idx,
    const float* __restrict__ wts, int* __restrict__ offs,
    int* __restrict__ perm, float* __restrict__ wt_slot, int* __restrict__ slot_of) {
  __shared__ int scur[NE];
  __shared__ int soff[NE + 1];
  if (threadIdx.x == 0) {
    int a = 0;
    for (int e = 0; e < NE; ++e) { soff[e] = a; scur[e] = a; a += counts[e]; }
    soff[NE] = a;
  }
  __syncthreads();
  if (threadIdx.x < NE + 1) offs[threadIdx.x] = soff[threadIdx.x];
  for (int t = threadIdx.x; t < T_TOK; t += 1024) {
    for (int k = 0; k < 2; ++k) {
      int e = idx[2 * t + k];
      int pos = atomicAdd(&scur[e], 1);
      perm[pos] = t;
      wt_slot[pos] = wts[2 * t + k];
      slot_of[2 * t + k] = pos;
    }
  }
}

// =====================================================================================
// ffn1: h = silu(X*W1^T) .* (X*W3^T)   BM=128, BN=128, BK=32, 512 thr, 8 waves (2x4)
// 3-deep circular LDS = 72 KiB -> 2 blocks/CU (16 waves). Counted vmcnt(3) steady.
// Per thread 3 gl_lds/tile (A,B1,B3: chunk tid of 512). Swizzle: pos p holds chunk
// p ^ ((row>>1)&3) -> 2-way bank on frag reads (free).
// LDS elems: A buf b @ b*4096, B1 @ 12288+b*4096, B3 @ 24576+b*4096  (36864 = 72KB)
// =====================================================================================
__global__ __launch_bounds__(512, 4) void ffn1_kernel(
    const u16* __restrict__ xb, const u16* __restrict__ w1b, const u16* __restrict__ w3b,
    const int* __restrict__ offs, const int* __restrict__ perm, u16* __restrict__ h) {
  __shared__ u16 smem[36864];
  int tid = threadIdx.x, wave = tid >> 6, lane = tid & 63;
  int wr = wave >> 2, wc = wave & 3;
  int lrow = lane & 15, lq = lane >> 4;
  // grid: 1136 = 8 XCD * 142; nid ordered bx-major so one XCD chunk covers all
  // m-blocks of ~1.1 f-tiles -> weight slices of all 8 experts (~4MB) stay in its L2
  int bid = blockIdx.x;
  int nid = (bid & 7) * 142 + (bid >> 3);
  int bx = nid / 71;    // f-tile 0..15
  int by = nid % 71;    // m-block
  int e = -1, mblk = 0;
  {
    int acc = 0;
    for (int i = 0; i < NE; ++i) {
      int c = offs[i + 1] - offs[i];
      int nb = (c + 127) >> 7;
      if (by < acc + nb) { e = i; mblk = by - acc; break; }
      acc += nb;
    }
  }
  if (e < 0) return;
  int seg = offs[e], cnt = offs[e + 1] - seg;
  int fBase = bx * 128;

  // staging: thread tid owns chunk tid of each 128x32 panel (row=tid>>2, pos=tid&3)
  int srow = tid >> 2, spos = tid & 3;
  int sch = spos ^ ((srow >> 1) & 3);
  const u16* gA;
  {
    int r = mblk * 128 + srow; if (r > cnt - 1) r = cnt - 1;
    gA = xb + (size_t)perm[seg + r] * DIM + sch * 8;
  }
  size_t wb = (size_t)e * DFF * DIM;
  const u16* gB1 = w1b + wb + (size_t)(fBase + srow) * DIM + sch * 8;
  const u16* gB3 = w3b + wb + (size_t)(fBase + srow) * DIM + sch * 8;

  int p8 = (lq ^ ((lrow >> 1) & 3)) * 8;
  int aoff[4], boff[2];
#pragma unroll
  for (int m = 0; m < 4; ++m) aoff[m] = (wr * 64 + m * 16 + lrow) * 32 + p8;
#pragma unroll
  for (int n = 0; n < 2; ++n) boff[n] = (wc * 32 + n * 16 + lrow) * 32 + p8;

  f32x4 acc1[4][2], acc3[4][2];
#pragma unroll
  for (int i = 0; i < 4; ++i)
#pragma unroll
    for (int j = 0; j < 2; ++j) {
      acc1[i][j] = (f32x4){0.f, 0.f, 0.f, 0.f};
      acc3[i][j] = (f32x4){0.f, 0.f, 0.f, 0.f};
    }

#define STAGE_F1(kt)                                                         \
  do {                                                                       \
    int kb = (kt) * 32, b = (kt) % 3;                                        \
    gl_lds16(gA + kb, &smem[b * 4096 + wave * 512]);                         \
    gl_lds16(gB1 + kb, &smem[12288 + b * 4096 + wave * 512]);                \
    gl_lds16(gB3 + kb, &smem[24576 + b * 4096 + wave * 512]);                \
  } while (0)

#define F1_TILE(T, STG, VM, BAR)                                             \
  do {                                                                       \
    int buf = (T) % 3;                                                       \
    const u16* lA = &smem[buf * 4096];                                       \
    const u16* lB1 = &smem[12288 + buf * 4096];                              \
    const u16* lB3 = &smem[24576 + buf * 4096];                              \
    bf16x8 a[4], b1[2], b3[2];                                               \
    _Pragma("unroll") for (int m = 0; m < 4; ++m)                            \
        a[m] = *(const bf16x8*)&lA[aoff[m]];                                 \
    _Pragma("unroll") for (int n = 0; n < 2; ++n) {                          \
      b1[n] = *(const bf16x8*)&lB1[boff[n]];                                 \
      b3[n] = *(const bf16x8*)&lB3[boff[n]];                                 \
    }                                                                        \
    if (STG) STAGE_F1((T) + 2);                                              \
    asm volatile("s_waitcnt lgkmcnt(0)" ::: "memory");                       \
    __builtin_amdgcn_sched_barrier(0);                                       \
    __builtin_amdgcn_s_setprio(1);                                           \
    _Pragma("unroll") for (int m = 0; m < 4; ++m)                            \
        _Pragma("unroll") for (int n = 0; n < 2; ++n) {                      \
      acc1[m][n] = __builtin_amdgcn_mfma_f32_16x16x32_bf16(a[m], b1[n], acc1[m][n], 0, 0, 0); \
      acc3[m][n] = __builtin_amdgcn_mfma_f32_16x16x32_bf16(a[m], b3[n], acc3[m][n], 0, 0, 0); \
    }                                                                        \
    __builtin_amdgcn_s_setprio(0);                                           \
    VM;                                                                      \
    if (BAR) __builtin_amdgcn_s_barrier();                                   \
  } while (0)

  // prologue: tiles 0,1 staged; wait tile 0 (leave tile 1's 3 loads in flight)
  STAGE_F1(0); STAGE_F1(1);
  VM3;
  __builtin_amdgcn_s_barrier();

  const int NT = DIM / 32;  // 32
  for (int t = 0; t < NT - 2; ++t) F1_TILE(t, true, VM3, true);
  F1_TILE(NT - 2, false, VM0, true);
  F1_TILE(NT - 1, false, VMN, false);
#undef F1_TILE
#undef STAGE_F1

  // epilogue: silu(c1)*c3 -> h
#pragma unroll
  for (int mi = 0; mi < 4; ++mi) {
#pragma unroll
    for (int jj = 0; jj < 4; ++jj) {
      int lr = mblk * 128 + wr * 64 + mi * 16 + lq * 4 + jj;
      if (lr < cnt) {
        size_t slot = (size_t)(seg + lr);
#pragma unroll
        for (int ni = 0; ni < 2; ++ni) {
          float c1v = acc1[mi][ni][jj], c3v = acc3[mi][ni][jj];
          float sv = c1v / (1.f + __expf(-c1v));
          int f = fBase + wc * 32 + ni * 16 + lrow;
          h[slot * DFF + f] = f2bf(sv * c3v);
        }
      }
    }
  }
}

// =====================================================================================
// ffn2: y = wt * (H * W2^T)   BM=128, BN=128, BK=32, 512 thr, 8 waves (2x4)
// 3-deep circular LDS = 48 KiB. Counted vmcnt(2) steady. 2 gl_lds/thread/tile.
// LDS elems: A buf b @ b*4096, B @ 12288+b*4096  (24576 = 48KB)
// =====================================================================================
__global__ __launch_bounds__(512, 4) void ffn2_kernel(
    const u16* __restrict__ h, const u16* __restrict__ w2b,
    const int* __restrict__ offs, const float* __restrict__ wt_slot,
    float* __restrict__ y) {
  __shared__ u16 smem[24576];
  int tid = threadIdx.x, wave = tid >> 6, lane = tid & 63;
  int wr = wave >> 2, wc = wave & 3;
  int lrow = lane & 15, lq = lane >> 4;
  int bid = blockIdx.x;                 // 568 = 8 * 71
  int nid = (bid & 7) * 71 + (bid >> 3);
  int bx = nid / 71;                    // d-tile 0..7
  int by = nid % 71;
  int e = -1, mblk = 0;
  {
    int acc = 0;
    for (int i = 0; i < NE; ++i) {
      int c = offs[i + 1] - offs[i];
      int nb = (c + 127) >> 7;
      if (by < acc + nb) { e = i; mblk = by - acc; break; }
      acc += nb;
    }
  }
  if (e < 0) return;
  int seg = offs[e], cnt = offs[e + 1] - seg;
  int dBase = bx * 128;

  int srow = tid >> 2, spos = tid & 3;
  int sch = spos ^ ((srow >> 1) & 3);
  const u16* gA;
  {
    int r = mblk * 128 + srow; if (r > cnt - 1) r = cnt - 1;
    gA = h + (size_t)(seg + r) * DFF + sch * 8;
  }
  const u16* gB = w2b + (size_t)e * DIM * DFF + (size_t)(dBase + srow) * DFF + sch * 8;

  int p8 = (lq ^ ((lrow >> 1) & 3)) * 8;
  int aoff[4], boff[2];
#pragma unroll
  for (int m = 0; m < 4; ++m) aoff[m] = (wr * 64 + m * 16 + lrow) * 32 + p8;
#pragma unroll
  for (int n = 0; n < 2; ++n) boff[n] = (wc * 32 + n * 16 + lrow) * 32 + p8;

  f32x4 acc[4][2];
#pragma unroll
  for (int i = 0; i < 4; ++i)
#pragma unroll
    for (int j = 0; j < 2; ++j) acc[i][j] = (f32x4){0.f, 0.f, 0.f, 0.f};

#define STAGE_F2(kt)                                                         \
  do {                                                                       \
    int kb = (kt) * 32, b = (kt) % 3;                                        \
    gl_lds16(gA + kb, &smem[b * 4096 + wave * 512]);                         \
    gl_lds16(gB + kb, &smem[12288 + b * 4096 + wave * 512]);                 \
  } while (0)

#define F2_TILE(T, STG, VM, BAR)                                             \
  do {                                                                       \
    int buf = (T) % 3;                                                       \
    const u16* lA = &smem[buf * 4096];                                       \
    const u16* lB = &smem[12288 + buf * 4096];                               \
    bf16x8 a[4], b[2];                                                       \
    _Pragma("unroll") for (int m = 0; m < 4; ++m)                            \
        a[m] = *(const bf16x8*)&lA[aoff[m]];                                 \
    _Pragma("unroll") for (int n = 0; n < 2; ++n)                            \
        b[n] = *(const bf16x8*)&lB[boff[n]];                                 \
    if (STG) STAGE_F2((T) + 2);                                              \
    asm volatile("s_waitcnt lgkmcnt(0)" ::: "memory");                       \
    __builtin_amdgcn_sched_barrier(0);                                       \
    __builtin_amdgcn_s_setprio(1);                                           \
    _Pragma("unroll") for (int m = 0; m < 4; ++m)                            \
        _Pragma("unroll") for (int n = 0; n < 2; ++n)                        \
            acc[m][n] = __builtin_amdgcn_mfma_f32_16x16x32_bf16(a[m], b[n], acc[m][n], 0, 0, 0); \
    __builtin_amdgcn_s_setprio(0);                                           \
    VM;                                                                      \
    if (BAR) __builtin_amdgcn_s_barrier();                                   \
  } while (0)

  STAGE_F2(0); STAGE_F2(1);
  VM2;
  __builtin_amdgcn_s_barrier();

  const int NT = DFF / 32;  // 64
  for (int t = 0; t < NT - 2; ++t) F2_TILE(t, true, VM2, true);
  F2_TILE(NT - 2, false, VM0, true);
  F2_TILE(NT - 1, false, VMN, false);
#undef F2_TILE
#undef STAGE_F2

#pragma unroll
  for (int mi = 0; mi < 4; ++mi) {
#pragma unroll
    for (int jj = 0; jj < 4; ++jj) {
      int lr = mblk * 128 + wr * 64 + mi * 16 + lq * 4 + jj;
      if (lr < cnt) {
        size_t slot = (size_t)(seg + lr);
        float wt = wt_slot[slot];
#pragma unroll
        for (int ni = 0; ni < 2; ++ni) {
          int d = dBase + wc * 32 + ni * 16 + lrow;
          y[slot * DIM + d] = wt * acc[mi][ni][jj];
        }
      }
    }
  }
}

// ---------------- combine: out[t] = y[slot0] + y[slot1] ----------------
__global__ __launch_bounds__(256) void combine_kernel(const float* __restrict__ y,
                                                      const int* __restrict__ slot_of,
                                                      float* __restrict__ out) {
  int t = blockIdx.x, dv = threadIdx.x;
  int s0 = slot_of[2 * t], s1 = slot_of[2 * t + 1];
  const float4* y4 = (const float4*)y;
  float4 a = y4[(size_t)s0 * 256 + dv];
  float4 b = y4[(size_t)s1 * 256 + dv];
  float4 r; r.x = a.x + b.x; r.y = a.y + b.y; r.z = a.z + b.z; r.w = a.w + b.w;
  ((float4*)out)[(size_t)t * 256 + dv] = r;
}

extern "C" void kernel_launch(void* const* d_in, const int* in_sizes, int n_in,
                              void* d_out, int out_size, void* d_ws, size_t ws_size,
                              hipStream_t stream) {
  const float* x  = (const float*)d_in[0];
  const float* gw = (const float*)d_in[1];
  const float* w1 = (const float*)d_in[2];
  const float* w2 = (const float*)d_in[3];
  const float* w3 = (const float*)d_in[4];
  float* out = (float*)d_out;

  char* ws = (char*)d_ws;
  size_t o = 0;
  u16* xb  = (u16*)(ws + o); o += (size_t)T_TOK * DIM * 2;
  u16* w1b = (u16*)(ws + o); o += (size_t)NE * DFF * DIM * 2;
  u16* w3b = (u16*)(ws + o); o += (size_t)NE * DFF * DIM * 2;
  u16* w2b = (u16*)(ws + o); o += (size_t)NE * DIM * DFF * 2;
  u16* h   = (u16*)(ws + o); o += (size_t)NSLOT * DFF * 2;
  float* y = (float*)(ws + o); o += (size_t)NSLOT * DIM * 4;
  int* idx      = (int*)(ws + o); o += NSLOT * 4;
  float* wts    = (float*)(ws + o); o += NSLOT * 4;
  int* slot_of  = (int*)(ws + o); o += NSLOT * 4;
  int* perm     = (int*)(ws + o); o += NSLOT * 4;
  float* wt_slot= (float*)(ws + o); o += NSLOT * 4;
  int* counts   = (int*)(ws + o); o += 16 * 4;
  int* offs     = (int*)(ws + o); o += 16 * 4;
  if (o > ws_size) return;

  cvtw_kernel<<<2048, 256, 0, stream>>>(w1, w2, w3, w1b, w2b, w3b, counts);
  gate_kernel<<<T_TOK / 4, 256, 0, stream>>>(x, gw, xb, idx, wts, counts);
  scan_scatter_kernel<<<1, 1024, 0, stream>>>(counts, idx, wts, offs, perm, wt_slot, slot_of);
  ffn1_kernel<<<1136, 512, 0, stream>>>(xb, w1b, w3b, offs, perm, h);
  ffn2_kernel<<<568, 512, 0, stream>>>(h, w2b, offs, wt_slot, y);
  combine_kernel<<<T_TOK, 256, 0, stream>>>(y, slot_of, out);
}

// Round 7
// 245.418 us; speedup vs baseline: 1.5433x; 1.3219x over previous
//
#include <hip/hip_runtime.h>
#include <hip/hip_bf16.h>
#include <cstdint>
#include <cstddef>

#define T_TOK 4096
#define DIM   1024
#define NE    8
#define DFF   2048
#define NSLOT 8192   // T_TOK * TOP_K

typedef __bf16 bf16x8 __attribute__((ext_vector_type(8)));
typedef float  f32x4  __attribute__((ext_vector_type(4)));
typedef unsigned short u16;
typedef unsigned short u16x8 __attribute__((ext_vector_type(8)));

__device__ __forceinline__ u16 f2bf(float f) {
  union { float f; uint32_t u; } v; v.f = f;
  uint32_t r = (v.u + 0x7FFFu + ((v.u >> 16) & 1u)) >> 16;
  return (u16)r;
}

typedef const __attribute__((address_space(1))) uint32_t* gas_ptr;
typedef __attribute__((address_space(3))) uint32_t* las_ptr;
__device__ __forceinline__ void gl_lds16(const void* g, void* l) {
  __builtin_amdgcn_global_load_lds((gas_ptr)g, (las_ptr)l, 16, 0, 0);
}

#define VM3 asm volatile("s_waitcnt vmcnt(3)" ::: "memory")
#define VM2 asm volatile("s_waitcnt vmcnt(2)" ::: "memory")
#define VM0 asm volatile("s_waitcnt vmcnt(0)" ::: "memory")
#define VMN ((void)0)

// =====================================================================================
// pre_kernel: blocks 0..1023 = gate (scores fp32, softmax, top-2, NO atomics; emits xb)
//             blocks 1024..3071 = fp32->bf16 weight conversion (grid-stride)
// =====================================================================================
__global__ __launch_bounds__(256) void pre_kernel(
    const float* __restrict__ x, const float* __restrict__ gw,
    const float* __restrict__ w1, const float* __restrict__ w2,
    const float* __restrict__ w3,
    u16* __restrict__ xb, u16* __restrict__ w1b, u16* __restrict__ w2b,
    u16* __restrict__ w3b, int* __restrict__ idx, float* __restrict__ wts) {
  __shared__ float sgw[NE * DIM];
  int b = blockIdx.x, tid = threadIdx.x;
  if (b < 1024) {
    // ---- gate ----
    const float4* gw4 = (const float4*)gw;
    float4* sgw4 = (float4*)sgw;
#pragma unroll
    for (int i = 0; i < 8; ++i) sgw4[tid + i * 256] = gw4[tid + i * 256];
    __syncthreads();
    int wave = tid >> 6, lane = tid & 63;
    int t = b * 4 + wave;
    float xv[16];
#pragma unroll
    for (int j = 0; j < 16; ++j) xv[j] = x[(size_t)t * DIM + lane + j * 64];
#pragma unroll
    for (int j = 0; j < 16; ++j) xb[(size_t)t * DIM + lane + j * 64] = f2bf(xv[j]);
    float s[NE];
#pragma unroll
    for (int e = 0; e < NE; ++e) {
      float a = 0.f;
#pragma unroll
      for (int j = 0; j < 16; ++j) a += xv[j] * sgw[e * DIM + lane + j * 64];
      s[e] = a;
    }
#pragma unroll
    for (int off = 32; off > 0; off >>= 1) {
#pragma unroll
      for (int e = 0; e < NE; ++e) s[e] += __shfl_xor(s[e], off, 64);
    }
    if (lane == 0) {
      float m = s[0];
#pragma unroll
      for (int e = 1; e < NE; ++e) m = fmaxf(m, s[e]);
      float p[NE];
#pragma unroll
      for (int e = 0; e < NE; ++e) p[e] = __expf(s[e] - m);
      int i0 = 0;
#pragma unroll
      for (int e = 1; e < NE; ++e) if (s[e] > s[i0]) i0 = e;
      int i1 = (i0 == 0) ? 1 : 0;
#pragma unroll
      for (int e = 0; e < NE; ++e) if (e != i1 && e != i0 && s[e] > s[i1]) i1 = e;
      float p0 = p[i0], p1 = p[i1], inv = 1.f / (p0 + p1);
      idx[2 * t] = i0; idx[2 * t + 1] = i1;
      wts[2 * t] = p0 * inv; wts[2 * t + 1] = p1 * inv;
    }
  } else {
    // ---- weight conversion ----
    const long n = (long)NE * DFF * DIM;
    long bid = b - 1024;
    long stride = 2048L * 256 * 8;
    for (long i = (bid * 256 + tid) * 8; i < 3 * n; i += stride) {
      const float* s; u16* d; long off;
      if (i < n)          { s = w1; d = w1b; off = i; }
      else if (i < 2 * n) { s = w2; d = w2b; off = i - n; }
      else                { s = w3; d = w3b; off = i - 2 * n; }
      float4 a = *(const float4*)(s + off);
      float4 c = *(const float4*)(s + off + 4);
      u16x8 r;
      r[0] = f2bf(a.x); r[1] = f2bf(a.y); r[2] = f2bf(a.z); r[3] = f2bf(a.w);
      r[4] = f2bf(c.x); r[5] = f2bf(c.y); r[6] = f2bf(c.z); r[7] = f2bf(c.w);
      *(u16x8*)(d + off) = r;
    }
  }
}

// =====================================================================================
// scan_scatter: single block. Ballot-histogram -> scan -> ballot-rank scatter.
// No dependence on any global counter state.
// =====================================================================================
__global__ __launch_bounds__(1024) void scan_scatter_kernel(
    const int* __restrict__ idx, const float* __restrict__ wts, int* __restrict__ offs,
    int* __restrict__ perm, float* __restrict__ wt_slot, int* __restrict__ slot_of) {
  __shared__ int shist[NE];
  __shared__ int soff[NE + 1];
  __shared__ int scur[NE];
  int tid = threadIdx.x, lane = tid & 63;
  if (tid < NE) shist[tid] = 0;
  __syncthreads();
  int eloc[8];
#pragma unroll
  for (int it = 0; it < 8; ++it) {
    int s = it * 1024 + tid;
    int e = idx[s];
    eloc[it] = e;
#pragma unroll
    for (int E = 0; E < NE; ++E) {
      unsigned long long m = __ballot(e == E);
      int leader = m ? (int)__builtin_ctzll(m) : -1;
      if (lane == leader) atomicAdd(&shist[E], (int)__popcll(m));
    }
  }
  __syncthreads();
  if (tid == 0) {
    int a = 0;
    for (int e = 0; e < NE; ++e) { soff[e] = a; scur[e] = a; a += shist[e]; }
    soff[NE] = a;
  }
  __syncthreads();
  if (tid < NE + 1) offs[tid] = soff[tid];
#pragma unroll
  for (int it = 0; it < 8; ++it) {
    int s = it * 1024 + tid;
    int e = eloc[it];
    int pos = 0;
#pragma unroll
    for (int E = 0; E < NE; ++E) {
      unsigned long long m = __ballot(e == E);
      int leader = m ? (int)__builtin_ctzll(m) : 0;
      int base = 0;
      if (m && lane == leader) base = atomicAdd(&scur[E], (int)__popcll(m));
      base = __shfl(base, leader, 64);
      if (e == E) pos = base + (int)__popcll(m & ((1ull << lane) - 1ull));
    }
    perm[pos] = s >> 1;
    wt_slot[pos] = wts[s];
    slot_of[s] = pos;
  }
}

// =====================================================================================
// ffn1: h = silu(X*W1^T) .* (X*W3^T)   BM=128, BN=128, BK=32, 512 thr, 8 waves (2x4)
// 3-deep circular LDS = 72 KiB -> 2 blocks/CU. Counted vmcnt(3) steady.
// =====================================================================================
__global__ __launch_bounds__(512, 4) void ffn1_kernel(
    const u16* __restrict__ xb, const u16* __restrict__ w1b, const u16* __restrict__ w3b,
    const int* __restrict__ offs, const int* __restrict__ perm, u16* __restrict__ h) {
  __shared__ u16 smem[36864];
  int tid = threadIdx.x, wave = tid >> 6, lane = tid & 63;
  int wr = wave >> 2, wc = wave & 3;
  int lrow = lane & 15, lq = lane >> 4;
  int bid = blockIdx.x;
  int nid = (bid & 7) * 142 + (bid >> 3);
  int bx = nid / 71;    // f-tile 0..15
  int by = nid % 71;    // m-block
  int e = -1, mblk = 0;
  {
    int acc = 0;
    for (int i = 0; i < NE; ++i) {
      int c = offs[i + 1] - offs[i];
      int nb = (c + 127) >> 7;
      if (by < acc + nb) { e = i; mblk = by - acc; break; }
      acc += nb;
    }
  }
  if (e < 0) return;
  int seg = offs[e], cnt = offs[e + 1] - seg;
  int fBase = bx * 128;

  int srow = tid >> 2, spos = tid & 3;
  int sch = spos ^ ((srow >> 1) & 3);
  const u16* gA;
  {
    int r = mblk * 128 + srow; if (r > cnt - 1) r = cnt - 1;
    gA = xb + (size_t)perm[seg + r] * DIM + sch * 8;
  }
  size_t wb = (size_t)e * DFF * DIM;
  const u16* gB1 = w1b + wb + (size_t)(fBase + srow) * DIM + sch * 8;
  const u16* gB3 = w3b + wb + (size_t)(fBase + srow) * DIM + sch * 8;

  int p8 = (lq ^ ((lrow >> 1) & 3)) * 8;
  int aoff[4], boff[2];
#pragma unroll
  for (int m = 0; m < 4; ++m) aoff[m] = (wr * 64 + m * 16 + lrow) * 32 + p8;
#pragma unroll
  for (int n = 0; n < 2; ++n) boff[n] = (wc * 32 + n * 16 + lrow) * 32 + p8;

  f32x4 acc1[4][2], acc3[4][2];
#pragma unroll
  for (int i = 0; i < 4; ++i)
#pragma unroll
    for (int j = 0; j < 2; ++j) {
      acc1[i][j] = (f32x4){0.f, 0.f, 0.f, 0.f};
      acc3[i][j] = (f32x4){0.f, 0.f, 0.f, 0.f};
    }

#define STAGE_F1(kt)                                                         \
  do {                                                                       \
    int kb = (kt) * 32, b = (kt) % 3;                                        \
    gl_lds16(gA + kb, &smem[b * 4096 + wave * 512]);                         \
    gl_lds16(gB1 + kb, &smem[12288 + b * 4096 + wave * 512]);                \
    gl_lds16(gB3 + kb, &smem[24576 + b * 4096 + wave * 512]);                \
  } while (0)

#define F1_TILE(T, STG, VM, BAR)                                             \
  do {                                                                       \
    int buf = (T) % 3;                                                       \
    const u16* lA = &smem[buf * 4096];                                       \
    const u16* lB1 = &smem[12288 + buf * 4096];                              \
    const u16* lB3 = &smem[24576 + buf * 4096];                              \
    bf16x8 a[4], b1[2], b3[2];                                               \
    _Pragma("unroll") for (int m = 0; m < 4; ++m)                            \
        a[m] = *(const bf16x8*)&lA[aoff[m]];                                 \
    _Pragma("unroll") for (int n = 0; n < 2; ++n) {                          \
      b1[n] = *(const bf16x8*)&lB1[boff[n]];                                 \
      b3[n] = *(const bf16x8*)&lB3[boff[n]];                                 \
    }                                                                        \
    if (STG) STAGE_F1((T) + 2);                                              \
    asm volatile("s_waitcnt lgkmcnt(0)" ::: "memory");                       \
    __builtin_amdgcn_sched_barrier(0);                                       \
    __builtin_amdgcn_s_setprio(1);                                           \
    _Pragma("unroll") for (int m = 0; m < 4; ++m)                            \
        _Pragma("unroll") for (int n = 0; n < 2; ++n) {                      \
      acc1[m][n] = __builtin_amdgcn_mfma_f32_16x16x32_bf16(a[m], b1[n], acc1[m][n], 0, 0, 0); \
      acc3[m][n] = __builtin_amdgcn_mfma_f32_16x16x32_bf16(a[m], b3[n], acc3[m][n], 0, 0, 0); \
    }                                                                        \
    __builtin_amdgcn_s_setprio(0);                                           \
    VM;                                                                      \
    if (BAR) __builtin_amdgcn_s_barrier();                                   \
  } while (0)

  STAGE_F1(0); STAGE_F1(1);
  VM3;
  __builtin_amdgcn_s_barrier();

  const int NT = DIM / 32;  // 32
  for (int t = 0; t < NT - 2; ++t) F1_TILE(t, true, VM3, true);
  F1_TILE(NT - 2, false, VM0, true);
  F1_TILE(NT - 1, false, VMN, false);
#undef F1_TILE
#undef STAGE_F1

#pragma unroll
  for (int mi = 0; mi < 4; ++mi) {
#pragma unroll
    for (int jj = 0; jj < 4; ++jj) {
      int lr = mblk * 128 + wr * 64 + mi * 16 + lq * 4 + jj;
      if (lr < cnt) {
        size_t slot = (size_t)(seg + lr);
#pragma unroll
        for (int ni = 0; ni < 2; ++ni) {
          float c1v = acc1[mi][ni][jj], c3v = acc3[mi][ni][jj];
          float sv = c1v / (1.f + __expf(-c1v));
          int f = fBase + wc * 32 + ni * 16 + lrow;
          h[slot * DFF + f] = f2bf(sv * c3v);
        }
      }
    }
  }
}

// =====================================================================================
// ffn2: y = wt * (H * W2^T)   BM=128, BN=128, BK=32, 512 thr, 8 waves (2x4)
// 3-deep circular LDS = 48 KiB. Counted vmcnt(2) steady.
// =====================================================================================
__global__ __launch_bounds__(512, 4) void ffn2_kernel(
    const u16* __restrict__ h, const u16* __restrict__ w2b,
    const int* __restrict__ offs, const float* __restrict__ wt_slot,
    float* __restrict__ y) {
  __shared__ u16 smem[24576];
  int tid = threadIdx.x, wave = tid >> 6, lane = tid & 63;
  int wr = wave >> 2, wc = wave & 3;
  int lrow = lane & 15, lq = lane >> 4;
  int bid = blockIdx.x;                 // 568 = 8 * 71
  int nid = (bid & 7) * 71 + (bid >> 3);
  int bx = nid / 71;                    // d-tile 0..7
  int by = nid % 71;
  int e = -1, mblk = 0;
  {
    int acc = 0;
    for (int i = 0; i < NE; ++i) {
      int c = offs[i + 1] - offs[i];
      int nb = (c + 127) >> 7;
      if (by < acc + nb) { e = i; mblk = by - acc; break; }
      acc += nb;
    }
  }
  if (e < 0) return;
  int seg = offs[e], cnt = offs[e + 1] - seg;
  int dBase = bx * 128;

  int srow = tid >> 2, spos = tid & 3;
  int sch = spos ^ ((srow >> 1) & 3);
  const u16* gA;
  {
    int r = mblk * 128 + srow; if (r > cnt - 1) r = cnt - 1;
    gA = h + (size_t)(seg + r) * DFF + sch * 8;
  }
  const u16* gB = w2b + (size_t)e * DIM * DFF + (size_t)(dBase + srow) * DFF + sch * 8;

  int p8 = (lq ^ ((lrow >> 1) & 3)) * 8;
  int aoff[4], boff[2];
#pragma unroll
  for (int m = 0; m < 4; ++m) aoff[m] = (wr * 64 + m * 16 + lrow) * 32 + p8;
#pragma unroll
  for (int n = 0; n < 2; ++n) boff[n] = (wc * 32 + n * 16 + lrow) * 32 + p8;

  f32x4 acc[4][2];
#pragma unroll
  for (int i = 0; i < 4; ++i)
#pragma unroll
    for (int j = 0; j < 2; ++j) acc[i][j] = (f32x4){0.f, 0.f, 0.f, 0.f};

#define STAGE_F2(kt)                                                         \
  do {                                                                       \
    int kb = (kt) * 32, b = (kt) % 3;                                        \
    gl_lds16(gA + kb, &smem[b * 4096 + wave * 512]);                         \
    gl_lds16(gB + kb, &smem[12288 + b * 4096 + wave * 512]);                 \
  } while (0)

#define F2_TILE(T, STG, VM, BAR)                                             \
  do {                                                                       \
    int buf = (T) % 3;                                                       \
    const u16* lA = &smem[buf * 4096];                                       \
    const u16* lB = &smem[12288 + buf * 4096];                               \
    bf16x8 a[4], b[2];                                                       \
    _Pragma("unroll") for (int m = 0; m < 4; ++m)                            \
        a[m] = *(const bf16x8*)&lA[aoff[m]];                                 \
    _Pragma("unroll") for (int n = 0; n < 2; ++n)                            \
        b[n] = *(const bf16x8*)&lB[boff[n]];                                 \
    if (STG) STAGE_F2((T) + 2);                                              \
    asm volatile("s_waitcnt lgkmcnt(0)" ::: "memory");                       \
    __builtin_amdgcn_sched_barrier(0);                                       \
    __builtin_amdgcn_s_setprio(1);                                           \
    _Pragma("unroll") for (int m = 0; m < 4; ++m)                            \
        _Pragma("unroll") for (int n = 0; n < 2; ++n)                        \
            acc[m][n] = __builtin_amdgcn_mfma_f32_16x16x32_bf16(a[m], b[n], acc[m][n], 0, 0, 0); \
    __builtin_amdgcn_s_setprio(0);                                           \
    VM;                                                                      \
    if (BAR) __builtin_amdgcn_s_barrier();                                   \
  } while (0)

  STAGE_F2(0); STAGE_F2(1);
  VM2;
  __builtin_amdgcn_s_barrier();

  const int NT = DFF / 32;  // 64
  for (int t = 0; t < NT - 2; ++t) F2_TILE(t, true, VM2, true);
  F2_TILE(NT - 2, false, VM0, true);
  F2_TILE(NT - 1, false, VMN, false);
#undef F2_TILE
#undef STAGE_F2

#pragma unroll
  for (int mi = 0; mi < 4; ++mi) {
#pragma unroll
    for (int jj = 0; jj < 4; ++jj) {
      int lr = mblk * 128 + wr * 64 + mi * 16 + lq * 4 + jj;
      if (lr < cnt) {
        size_t slot = (size_t)(seg + lr);
        float wt = wt_slot[slot];
#pragma unroll
        for (int ni = 0; ni < 2; ++ni) {
          int d = dBase + wc * 32 + ni * 16 + lrow;
          y[slot * DIM + d] = wt * acc[mi][ni][jj];
        }
      }
    }
  }
}

// ---------------- combine: out[t] = y[slot0] + y[slot1] ----------------
__global__ __launch_bounds__(256) void combine_kernel(const float* __restrict__ y,
                                                      const int* __restrict__ slot_of,
                                                      float* __restrict__ out) {
  int t = blockIdx.x, dv = threadIdx.x;
  int s0 = slot_of[2 * t], s1 = slot_of[2 * t + 1];
  const float4* y4 = (const float4*)y;
  float4 a = y4[(size_t)s0 * 256 + dv];
  float4 b = y4[(size_t)s1 * 256 + dv];
  float4 r; r.x = a.x + b.x; r.y = a.y + b.y; r.z = a.z + b.z; r.w = a.w + b.w;
  ((float4*)out)[(size_t)t * 256 + dv] = r;
}

extern "C" void kernel_launch(void* const* d_in, const int* in_sizes, int n_in,
                              void* d_out, int out_size, void* d_ws, size_t ws_size,
                              hipStream_t stream) {
  const float* x  = (const float*)d_in[0];
  const float* gw = (const float*)d_in[1];
  const float* w1 = (const float*)d_in[2];
  const float* w2 = (const float*)d_in[3];
  const float* w3 = (const float*)d_in[4];
  float* out = (float*)d_out;

  char* ws = (char*)d_ws;
  size_t o = 0;
  u16* xb  = (u16*)(ws + o); o += (size_t)T_TOK * DIM * 2;
  u16* w1b = (u16*)(ws + o); o += (size_t)NE * DFF * DIM * 2;
  u16* w3b = (u16*)(ws + o); o += (size_t)NE * DFF * DIM * 2;
  u16* w2b = (u16*)(ws + o); o += (size_t)NE * DIM * DFF * 2;
  u16* h   = (u16*)(ws + o); o += (size_t)NSLOT * DFF * 2;
  float* y = (float*)(ws + o); o += (size_t)NSLOT * DIM * 4;
  int* idx      = (int*)(ws + o); o += NSLOT * 4;
  float* wts    = (float*)(ws + o); o += NSLOT * 4;
  int* slot_of  = (int*)(ws + o); o += NSLOT * 4;
  int* perm     = (int*)(ws + o); o += NSLOT * 4;
  float* wt_slot= (float*)(ws + o); o += NSLOT * 4;
  int* offs     = (int*)(ws + o); o += 16 * 4;
  if (o > ws_size) return;

  pre_kernel<<<3072, 256, 0, stream>>>(x, gw, w1, w2, w3, xb, w1b, w2b, w3b, idx, wts);
  scan_scatter_kernel<<<1, 1024, 0, stream>>>(idx, wts, offs, perm, wt_slot, slot_of);
  ffn1_kernel<<<1136, 512, 0, stream>>>(xb, w1b, w3b, offs, perm, h);
  ffn2_kernel<<<568, 512, 0, stream>>>(h, w2b, offs, wt_slot, y);
  combine_kernel<<<T_TOK, 256, 0, stream>>>(y, slot_of, out);
}